// Round 4
// baseline (1254.515 us; speedup 1.0000x reference)
//
#include <hip/hip_runtime.h>
#include <math.h>

#define N_TOK 32768
#define M_EMB 1024
#define D_DIM 128

// workspace layout (bytes)
#define WS_EH  0                        // bf16 e_hi[1024][128]   (256 KB)
#define WS_EL  262144                   // bf16 e_lo[1024][128]   (256 KB)
#define WS_TH  524288                   // bf16 et_hi[128][1024]  (256 KB)
#define WS_TL  786432                   // bf16 et_lo[128][1024]  (256 KB)
#define WS_E2  1048576                  // float e2[1024]
#define WS_CNT (WS_E2 + 4096)           // int counts[1024]
#define WS_SS  (WS_CNT + 4096)          // float sum((x-q)^2)
#define WS_ENT (WS_SS + 4)              // float sum(p*logp)

typedef float  f32x4  __attribute__((ext_vector_type(4)));
typedef short  s16x8  __attribute__((ext_vector_type(8)));
typedef short  s16x4  __attribute__((ext_vector_type(4)));
typedef __bf16 bf16x8 __attribute__((ext_vector_type(8)));

__device__ __forceinline__ ushort f2bf(float f) {
    unsigned x = __float_as_uint(f);
    unsigned r = (x + 0x7fffu + ((x >> 16) & 1u)) >> 16;
    return (ushort)r;
}
__device__ __forceinline__ float bf2f(ushort h) {
    return __uint_as_float(((unsigned)h) << 16);
}
__device__ __forceinline__ f32x4 mfma_k32(s16x8 a, s16x8 b, f32x4 c) {
    return __builtin_amdgcn_mfma_f32_16x16x32_bf16(
        __builtin_bit_cast(bf16x8, a), __builtin_bit_cast(bf16x8, b), c, 0, 0, 0);
}
__device__ __forceinline__ f32x4 mfma_k16(s16x4 a, s16x4 b, f32x4 c) {
#if __has_builtin(__builtin_amdgcn_mfma_f32_16x16x16bf16_1k)
    return __builtin_amdgcn_mfma_f32_16x16x16bf16_1k(a, b, c, 0, 0, 0);
#else
    asm("v_mfma_f32_16x16x16_bf16 %0, %1, %2, %0" : "+v"(c) : "v"(a), "v"(b));
    return c;
#endif
}

// Convert embedding to bf16 hi/lo in row-major and transposed layouts; e2; zero accums.
__global__ void k_prep(const float* __restrict__ emb, char* ws) {
    __shared__ ushort th_s[16][128];
    __shared__ ushort tl_s[16][128];
    if (blockIdx.x == 0) {
        int* cnt = (int*)(ws + WS_CNT);
        for (int i = threadIdx.x; i < M_EMB; i += 256) cnt[i] = 0;
        if (threadIdx.x == 0) {
            *(float*)(ws + WS_SS) = 0.f;
            *(float*)(ws + WS_ENT) = 0.f;
        }
    }
    ushort* eh = (ushort*)(ws + WS_EH);
    ushort* el = (ushort*)(ws + WS_EL);
    ushort* th = (ushort*)(ws + WS_TH);
    ushort* tl = (ushort*)(ws + WS_TL);
    float* e2 = (float*)(ws + WS_E2);
    const int m0 = blockIdx.x * 16;
    const int t = threadIdx.x;
    #pragma unroll
    for (int ii = 0; ii < 8; ii++) {
        int idx = t + ii * 256;          // 0..2047
        int mi = idx >> 7, k = idx & 127;
        float v = emb[(size_t)(m0 + mi) * D_DIM + k];
        ushort hi = f2bf(v);
        ushort lo = f2bf(v - bf2f(hi));
        eh[(size_t)(m0 + mi) * D_DIM + k] = hi;
        el[(size_t)(m0 + mi) * D_DIM + k] = lo;
        th_s[mi][k] = hi;
        tl_s[mi][k] = lo;
    }
    __syncthreads();
    {
        int k = t >> 1, half = t & 1;
        s16x8 vh, vl;
        #pragma unroll
        for (int j = 0; j < 8; j++) {
            vh[j] = (short)th_s[half * 8 + j][k];
            vl[j] = (short)tl_s[half * 8 + j][k];
        }
        *(s16x8*)(th + (size_t)k * M_EMB + m0 + half * 8) = vh;
        *(s16x8*)(tl + (size_t)k * M_EMB + m0 + half * 8) = vl;
    }
    if (t < 16) {
        float s = 0.f;
        const float* er = emb + (size_t)(m0 + t) * D_DIM;
        #pragma unroll 4
        for (int k = 0; k < 128; k++) s += er[k] * er[k];
        e2[m0 + t] = s;
    }
}

// Flash-style fused kernel, m-split 4 ways across the block's 4 waves.
// Block = one 32-row tile; wave w streams m in [256w, 256w+256).
// Main loop has NO barriers; partial qacc/stats merged via LDS at the end.
__global__ __launch_bounds__(256, 4) void k_main(
    const float* __restrict__ x, const float* __restrict__ emb,
    const float* __restrict__ lvq, const float* __restrict__ u,
    float* __restrict__ out, char* __restrict__ ws)
{
    __shared__ float lds_q[32][4][64];                    // 32 KB, [idx][wave][lane]
    __shared__ float lds_S[4][2][16], lds_T[4][2][16], lds_Sg[4][2][16];
    __shared__ float lds_b1[4][2][16], lds_b2[4][2][16];
    __shared__ int   lds_i1[4][2][16], lds_i2[4][2][16];

    const int t = threadIdx.x;
    const int w = t >> 6;            // wave 0..3 -> m-quarter
    const int lane = t & 63;
    const int l15 = lane & 15;
    const int h = lane >> 4;
    const int n0 = blockIdx.x * 32;

    const float* e2g = (const float*)(ws + WS_E2);
    int* cnt = (int*)(ws + WS_CNT);
    float* ws_ss = (float*)(ws + WS_SS);
    float* ws_ent = (float*)(ws + WS_ENT);
    const s16x8* EH = (const s16x8*)(ws + WS_EH);
    const s16x8* EL = (const s16x8*)(ws + WS_EL);
    const s16x4* TH4 = (const s16x4*)(ws + WS_TH);
    const s16x4* TL4 = (const s16x4*)(ws + WS_TL);

    const float prec = expf(-lvq[0]);
    const float hp = 0.5f * prec;

    // ---- x B-fragments (rows n0 + rt*16 + l15), split hi/lo ----
    s16x8 xh[2][4], xl[2][4];
    #pragma unroll
    for (int rt = 0; rt < 2; rt++) {
        const float* xr = x + (size_t)(n0 + rt * 16 + l15) * D_DIM;
        #pragma unroll
        for (int ks = 0; ks < 4; ks++) {
            const int k0 = ks * 32 + h * 8;
            float4 v0 = *(const float4*)(xr + k0);
            float4 v1 = *(const float4*)(xr + k0 + 4);
            float vv[8] = {v0.x, v0.y, v0.z, v0.w, v1.x, v1.y, v1.z, v1.w};
            s16x8 hi8, lo8;
            #pragma unroll
            for (int j = 0; j < 8; j++) {
                ushort hi = f2bf(vv[j]);
                hi8[j] = (short)hi;
                lo8[j] = (short)f2bf(vv[j] - bf2f(hi));
            }
            xh[rt][ks] = hi8;
            xl[rt][ks] = lo8;
        }
    }

    const f32x4 zz = {0.f, 0.f, 0.f, 0.f};
    f32x4 qacc[2][8];
    #pragma unroll
    for (int rt = 0; rt < 2; rt++)
        #pragma unroll
        for (int dt = 0; dt < 8; dt++) qacc[rt][dt] = zz;

    float S[2] = {0.f, 0.f}, T[2] = {0.f, 0.f}, Sg[2] = {0.f, 0.f};
    float bv1[2] = {-INFINITY, -INFINITY}, bv2[2] = {-INFINITY, -INFINITY};
    int bi1[2] = {M_EMB, M_EMB}, bi2[2] = {M_EMB, M_EMB};

    const float* urow[2] = {u + (size_t)(n0 + l15) * M_EMB,
                            u + (size_t)(n0 + 16 + l15) * M_EMB};
    const float EPS = 1.1920929e-07f, OME = 0.99999988f;

    #pragma unroll 1
    for (int mc = w * 8; mc < w * 8 + 8; mc++) {
        const int mb = mc * 32;
        // hoist the HBM-latency u loads for this whole chunk ahead of the MFMAs
        float4 uvv[2][2];
        #pragma unroll
        for (int t2 = 0; t2 < 2; t2++)
            #pragma unroll
            for (int rt = 0; rt < 2; rt++)
                uvv[t2][rt] = *(const float4*)(urow[rt] + mb + t2 * 16 + h * 4);
        #pragma unroll
        for (int t2 = 0; t2 < 2; t2++) {
            const int msub = mb + t2 * 16;
            // A-fragments: E rows (msub + l15), shared across both n-tiles
            s16x8 ah[4], al[4];
            #pragma unroll
            for (int ks = 0; ks < 4; ks++) {
                const int bidx = (msub + l15) * 16 + ks * 4 + h;
                ah[ks] = EH[bidx];
                al[ks] = EL[bidx];
            }
            // scores: D[m = 4h+j][n = l15] per rt, 3-way bf16 split
            f32x4 sc[2];
            #pragma unroll
            for (int rt = 0; rt < 2; rt++) {
                f32x4 aa = zz, ab = zz, ac = zz;
                #pragma unroll
                for (int ks = 0; ks < 4; ks++) {
                    aa = mfma_k32(ah[ks], xh[rt][ks], aa);
                    ab = mfma_k32(al[ks], xh[rt][ks], ab);
                    ac = mfma_k32(ah[ks], xl[rt][ks], ac);
                }
                #pragma unroll
                for (int j = 0; j < 4; j++) sc[rt][j] = aa[j] + ab[j] + ac[j];
            }
            const float4 e2v = *(const float4*)(e2g + msub + h * 4);
            #pragma unroll
            for (int rt = 0; rt < 2; rt++) {
                const float uu[4] = {uvv[t2][rt].x, uvv[t2][rt].y, uvv[t2][rt].z, uvv[t2][rt].w};
                const float ee[4] = {e2v.x, e2v.y, e2v.z, e2v.w};
                ushort pb[4];
                #pragma unroll
                for (int j = 0; j < 4; j++) {
                    const int m = msub + h * 4 + j;
                    const float v = prec * sc[rt][j] - hp * ee[j];
                    // top-2 (ascending m within lane, keep-first ties)
                    if (v > bv1[rt]) {
                        bv2[rt] = bv1[rt]; bi2[rt] = bi1[rt];
                        bv1[rt] = v; bi1[rt] = m;
                    } else if (v > bv2[rt]) {
                        bv2[rt] = v; bi2[rt] = m;
                    }
                    // entropy sums (no max shift needed: |v| <~ 40)
                    const float e = __expf(v);
                    S[rt] += e; T[rt] += e * v;
                    // gumbel: p~ = exp(v + g) = e / (-log u); series for u->1
                    const float uc = fminf(fmaxf(uu[j], EPS), OME);
                    const float d1 = 1.0f - uc;
                    const float Lser = d1 * (1.0f + d1 * (0.5f + d1 * (0.33333334f + d1 * 0.25f)));
                    const float Lnat = -__logf(uc);
                    const float L = (d1 < 0.03125f) ? Lser : Lnat;
                    const float pt = e * __builtin_amdgcn_rcpf(L);
                    Sg[rt] += pt;
                    pb[j] = f2bf(pt);
                }
                // PV: p~ tile is already in mfma_16x16x16 A-layout (row n=l15, k=4h+j)
                s16x4 pa;
                pa[0] = (short)pb[0]; pa[1] = (short)pb[1];
                pa[2] = (short)pb[2]; pa[3] = (short)pb[3];
                const int bbase = l15 * 256 + (mb >> 2) + t2 * 4 + h;
                #pragma unroll
                for (int dt = 0; dt < 8; dt++) {
                    const int bidx = dt * 4096 + bbase;
                    qacc[rt][dt] = mfma_k16(pa, TH4[bidx], qacc[rt][dt]);
                    qacc[rt][dt] = mfma_k16(pa, TL4[bidx], qacc[rt][dt]);
                }
            }
        }
    }

    // ---- in-wave reduce across h-group (lanes l, l^16, l^32, l^48) ----
    #pragma unroll
    for (int rt = 0; rt < 2; rt++) {
        #pragma unroll
        for (int off = 16; off <= 32; off <<= 1) {
            S[rt] += __shfl_xor(S[rt], off);
            T[rt] += __shfl_xor(T[rt], off);
            Sg[rt] += __shfl_xor(Sg[rt], off);
            const float ov1 = __shfl_xor(bv1[rt], off); const int oi1 = __shfl_xor(bi1[rt], off);
            const float ov2 = __shfl_xor(bv2[rt], off); const int oi2 = __shfl_xor(bi2[rt], off);
            if (ov1 > bv1[rt] || (ov1 == bv1[rt] && oi1 < bi1[rt])) {
                if (bv1[rt] > ov2 || (bv1[rt] == ov2 && bi1[rt] < oi2)) { bv2[rt] = bv1[rt]; bi2[rt] = bi1[rt]; }
                else { bv2[rt] = ov2; bi2[rt] = oi2; }
                bv1[rt] = ov1; bi1[rt] = oi1;
            } else if (ov1 > bv2[rt] || (ov1 == bv2[rt] && oi1 < bi2[rt])) {
                bv2[rt] = ov1; bi2[rt] = oi1;
            }
        }
    }

    // ---- publish per-wave partial stats ----
    if (lane < 16) {
        #pragma unroll
        for (int rt = 0; rt < 2; rt++) {
            lds_S[w][rt][lane] = S[rt];
            lds_T[w][rt][lane] = T[rt];
            lds_Sg[w][rt][lane] = Sg[rt];
            lds_b1[w][rt][lane] = bv1[rt]; lds_i1[w][rt][lane] = bi1[rt];
            lds_b2[w][rt][lane] = bv2[rt]; lds_i2[w][rt][lane] = bi2[rt];
        }
    }
    __syncthreads();

    // ---- merge stats across the 4 m-quarters (every lane, row = l15) ----
    float Sm[2], Tm[2], Sgm[2], B1[2], B2[2];
    int I1[2], I2[2];
    #pragma unroll
    for (int rt = 0; rt < 2; rt++) {
        float sS = 0.f, sT = 0.f, sG = 0.f, b1 = -INFINITY, b2 = -INFINITY;
        int i1 = M_EMB, i2 = M_EMB;
        #pragma unroll
        for (int pw = 0; pw < 4; pw++) {
            sS += lds_S[pw][rt][l15];
            sT += lds_T[pw][rt][l15];
            sG += lds_Sg[pw][rt][l15];
            const float v1 = lds_b1[pw][rt][l15]; const int ii1 = lds_i1[pw][rt][l15];
            const float v2 = lds_b2[pw][rt][l15]; const int ii2 = lds_i2[pw][rt][l15];
            if (v1 > b1 || (v1 == b1 && ii1 < i1)) { b2 = b1; i2 = i1; b1 = v1; i1 = ii1; }
            else if (v1 > b2 || (v1 == b2 && ii1 < i2)) { b2 = v1; i2 = ii1; }
            if (v2 > b2 || (v2 == b2 && ii2 < i2)) { b2 = v2; i2 = ii2; }
        }
        Sm[rt] = sS; Tm[rt] = sT; Sgm[rt] = sG;
        B1[rt] = b1; I1[rt] = i1; B2[rt] = b2; I2[rt] = i2;
    }
    float invv[2][4];
    #pragma unroll
    for (int rt = 0; rt < 2; rt++)
        #pragma unroll
        for (int j = 0; j < 4; j++)
            invv[rt][j] = 1.0f / __shfl(Sgm[rt], 4 * h + j);

    // ---- role work: waves 0/1 recheck rt 0/1; wave 2 entropy ----
    if (w < 2) {
        const int rt = w;
        const float* xr = x + (size_t)(n0 + rt * 16 + l15) * D_DIM + h * 32;
        const float* ea = emb + (size_t)I1[rt] * D_DIM + h * 32;
        const float* eb = emb + (size_t)I2[rt] * D_DIM + h * 32;
        float s1 = 0.f, s2 = 0.f;
        #pragma unroll
        for (int i = 0; i < 8; i++) {
            const float4 xv = ((const float4*)xr)[i];
            const float4 av = ((const float4*)ea)[i];
            const float4 bb = ((const float4*)eb)[i];
            s1 += xv.x * av.x + xv.y * av.y + xv.z * av.z + xv.w * av.w;
            s2 += xv.x * bb.x + xv.y * bb.y + xv.z * bb.z + xv.w * bb.w;
        }
        #pragma unroll
        for (int off = 16; off <= 32; off <<= 1) {
            s1 += __shfl_xor(s1, off);
            s2 += __shfl_xor(s2, off);
        }
        const float g1 = prec * s1 - hp * e2g[I1[rt]];
        const float g2 = prec * s2 - hp * e2g[I2[rt]];
        const int win = (g2 > g1 || (g2 == g1 && I2[rt] < I1[rt])) ? I2[rt] : I1[rt];
        if (lane < 16) {
            out[(size_t)N_TOK * D_DIM + n0 + rt * 16 + lane] = (float)win;
            atomicAdd(&cnt[win], 1);
        }
    } else if (w == 2) {
        float ent = (Tm[0] / Sm[0] - __logf(Sm[0])) + (Tm[1] / Sm[1] - __logf(Sm[1]));
        #pragma unroll
        for (int off = 1; off <= 8; off <<= 1) ent += __shfl_xor(ent, off);
        if (lane == 0) atomicAdd(ws_ent, ent);
    }

    // ---- merge qacc partials in two 32 KB LDS chunks; each wave owns 2 dt ----
    float sslw = 0.f;
    #pragma unroll 1
    for (int rtc = 0; rtc < 2; rtc++) {
        if (rtc) __syncthreads();        // prev chunk fully read before overwrite
        #pragma unroll
        for (int dt = 0; dt < 8; dt++)
            #pragma unroll
            for (int j = 0; j < 4; j++)
                lds_q[dt * 4 + j][w][lane] = qacc[rtc][dt][j];
        __syncthreads();
        #pragma unroll
        for (int dp = 0; dp < 2; dp++) {
            const int dt = 2 * w + dp;
            #pragma unroll
            for (int j = 0; j < 4; j++) {
                const float qm = lds_q[dt * 4 + j][0][lane] + lds_q[dt * 4 + j][1][lane]
                               + lds_q[dt * 4 + j][2][lane] + lds_q[dt * 4 + j][3][lane];
                const float q = qm * invv[rtc][j];
                const int n = n0 + rtc * 16 + 4 * h + j;
                const int d = dt * 16 + l15;
                out[(size_t)n * D_DIM + d] = q;
                const float df = x[(size_t)n * D_DIM + d] - q;
                sslw += df * df;
            }
        }
    }
    #pragma unroll
    for (int off = 1; off <= 32; off <<= 1) sslw += __shfl_xor(sslw, off);
    if (lane == 0) atomicAdd(ws_ss, sslw);
}

__global__ void k_final(const float* __restrict__ lvq, float* __restrict__ out, char* ws) {
    const int* cnt = (const int*)(ws + WS_CNT);
    float s = 0.f;
    for (int i = threadIdx.x; i < M_EMB; i += 256) {
        float avg = (float)cnt[i] * (1.f / N_TOK);
        s += avg * logf(avg + 1e-10f);
    }
    #pragma unroll
    for (int off = 32; off >= 1; off >>= 1) s += __shfl_down(s, off);
    __shared__ float p[4];
    if ((threadIdx.x & 63) == 0) p[threadIdx.x >> 6] = s;
    __syncthreads();
    if (threadIdx.x == 0) {
        float tot = p[0] + p[1] + p[2] + p[3];
        float perp = expf(-tot);
        float prec = expf(-lvq[0]);
        float loss = 0.5f * prec * (*(float*)(ws + WS_SS)) + (*(float*)(ws + WS_ENT));
        out[(size_t)N_TOK * D_DIM + N_TOK] = loss;
        out[(size_t)N_TOK * D_DIM + N_TOK + 1] = perp;
    }
}

extern "C" void kernel_launch(void* const* d_in, const int* in_sizes, int n_in,
                              void* d_out, int out_size, void* d_ws, size_t ws_size,
                              hipStream_t stream) {
    const float* x   = (const float*)d_in[0];
    const float* emb = (const float*)d_in[1];
    const float* lvq = (const float*)d_in[2];
    const float* u   = (const float*)d_in[3];
    float* out = (float*)d_out;
    char* ws = (char*)d_ws;
    k_prep<<<dim3(M_EMB / 16), dim3(256), 0, stream>>>(emb, ws);
    k_main<<<dim3(N_TOK / 32), dim3(256), 0, stream>>>(x, emb, lvq, u, out, ws);
    k_final<<<dim3(1), dim3(256), 0, stream>>>(lvq, out, ws);
}

// Round 8
// 597.502 us; speedup vs baseline: 2.0996x; 2.0996x over previous
//
#include <hip/hip_runtime.h>
#include <math.h>

#define N_TOK 32768
#define M_EMB 1024
#define D_DIM 128

// workspace layout (bytes)
#define WS_EH  0                        // bf16 e_hi[1024][128]   (256 KB)
#define WS_EL  262144                   // bf16 e_lo[1024][128]   (256 KB)
#define WS_TH  524288                   // bf16 et_hi[128][1024]  (256 KB)
#define WS_TL  786432                   // bf16 et_lo[128][1024]  (256 KB)
#define WS_E2  1048576                  // float e2[1024]
#define WS_CNT (WS_E2 + 4096)           // int counts[1024]
#define WS_SS  (WS_CNT + 4096)          // float sum((x-q)^2)
#define WS_ENT (WS_SS + 4)              // float sum(p*logp)
#define WS_DONE (WS_ENT + 4)            // int: blocks-finished counter

typedef float  f32x4  __attribute__((ext_vector_type(4)));
typedef short  s16x8  __attribute__((ext_vector_type(8)));
typedef short  s16x4  __attribute__((ext_vector_type(4)));
typedef __bf16 bf16x8 __attribute__((ext_vector_type(8)));

__device__ __forceinline__ ushort f2bf(float f) {
    unsigned x = __float_as_uint(f);
    unsigned r = (x + 0x7fffu + ((x >> 16) & 1u)) >> 16;
    return (ushort)r;
}
__device__ __forceinline__ float bf2f(ushort h) {
    return __uint_as_float(((unsigned)h) << 16);
}
__device__ __forceinline__ f32x4 mfma_k32(s16x8 a, s16x8 b, f32x4 c) {
    return __builtin_amdgcn_mfma_f32_16x16x32_bf16(
        __builtin_bit_cast(bf16x8, a), __builtin_bit_cast(bf16x8, b), c, 0, 0, 0);
}
__device__ __forceinline__ f32x4 mfma_k16(s16x4 a, s16x4 b, f32x4 c) {
#if __has_builtin(__builtin_amdgcn_mfma_f32_16x16x16bf16_1k)
    return __builtin_amdgcn_mfma_f32_16x16x16bf16_1k(a, b, c, 0, 0, 0);
#else
    asm("v_mfma_f32_16x16x16_bf16 %0, %1, %2, %0" : "+v"(c) : "v"(a), "v"(b));
    return c;
#endif
}

// Convert embedding to bf16 hi/lo in row-major and transposed layouts; e2; zero accums.
__global__ void k_prep(const float* __restrict__ emb, char* ws) {
    __shared__ ushort th_s[16][128];
    __shared__ ushort tl_s[16][128];
    if (blockIdx.x == 0) {
        int* cnt = (int*)(ws + WS_CNT);
        for (int i = threadIdx.x; i < M_EMB; i += 256) cnt[i] = 0;
        if (threadIdx.x == 0) {
            *(float*)(ws + WS_SS) = 0.f;
            *(float*)(ws + WS_ENT) = 0.f;
            *(int*)(ws + WS_DONE) = 0;
        }
    }
    ushort* eh = (ushort*)(ws + WS_EH);
    ushort* el = (ushort*)(ws + WS_EL);
    ushort* th = (ushort*)(ws + WS_TH);
    ushort* tl = (ushort*)(ws + WS_TL);
    float* e2 = (float*)(ws + WS_E2);
    const int m0 = blockIdx.x * 16;
    const int t = threadIdx.x;
    #pragma unroll
    for (int ii = 0; ii < 8; ii++) {
        int idx = t + ii * 256;          // 0..2047
        int mi = idx >> 7, k = idx & 127;
        float v = emb[(size_t)(m0 + mi) * D_DIM + k];
        ushort hi = f2bf(v);
        ushort lo = f2bf(v - bf2f(hi));
        eh[(size_t)(m0 + mi) * D_DIM + k] = hi;
        el[(size_t)(m0 + mi) * D_DIM + k] = lo;
        th_s[mi][k] = hi;
        tl_s[mi][k] = lo;
    }
    __syncthreads();
    {
        int k = t >> 1, half = t & 1;
        s16x8 vh, vl;
        #pragma unroll
        for (int j = 0; j < 8; j++) {
            vh[j] = (short)th_s[half * 8 + j][k];
            vl[j] = (short)tl_s[half * 8 + j][k];
        }
        *(s16x8*)(th + (size_t)k * M_EMB + m0 + half * 8) = vh;
        *(s16x8*)(tl + (size_t)k * M_EMB + m0 + half * 8) = vl;
    }
    if (t < 16) {
        float s = 0.f;
        const float* er = emb + (size_t)(m0 + t) * D_DIM;
        #pragma unroll 4
        for (int k = 0; k < 128; k++) s += er[k] * er[k];
        e2[m0 + t] = s;
    }
}

// Flash-style fused kernel, m-split 4 ways across the block's 4 waves.
// Block = one 32-row tile; wave w streams m in [256w, 256w+256).
// Main loop has NO barriers; partial qacc/stats merged via LDS at the end.
// launch_bounds(256,2): VGPR cap 256 -> compiler picks ~128-150, NO spill
// (round-4's (256,4) capped VGPR at 64 -> 3.2 GB scratch traffic, 2.4x slower).
__global__ __launch_bounds__(256, 2) void k_main(
    const float* __restrict__ x, const float* __restrict__ emb,
    const float* __restrict__ lvq, const float* __restrict__ u,
    float* __restrict__ out, char* __restrict__ ws)
{
    __shared__ float lds_q[32][4][64];                    // 32 KB, [idx][wave][lane]
    __shared__ float lds_S[4][2][16], lds_T[4][2][16], lds_Sg[4][2][16];
    __shared__ float lds_b1[4][2][16], lds_b2[4][2][16];
    __shared__ int   lds_i1[4][2][16], lds_i2[4][2][16];
    __shared__ int   last_flag;
    __shared__ float fin[4];

    const int t = threadIdx.x;
    const int w = t >> 6;            // wave 0..3 -> m-quarter
    const int lane = t & 63;
    const int l15 = lane & 15;
    const int h = lane >> 4;
    const int n0 = blockIdx.x * 32;

    const float* e2g = (const float*)(ws + WS_E2);
    int* cnt = (int*)(ws + WS_CNT);
    float* ws_ss = (float*)(ws + WS_SS);
    float* ws_ent = (float*)(ws + WS_ENT);
    const s16x8* EH = (const s16x8*)(ws + WS_EH);
    const s16x8* EL = (const s16x8*)(ws + WS_EL);
    const s16x4* TH4 = (const s16x4*)(ws + WS_TH);
    const s16x4* TL4 = (const s16x4*)(ws + WS_TL);

    const float prec = expf(-lvq[0]);
    const float hp = 0.5f * prec;

    // ---- x B-fragments (rows n0 + rt*16 + l15), split hi/lo ----
    s16x8 xh[2][4], xl[2][4];
    #pragma unroll
    for (int rt = 0; rt < 2; rt++) {
        const float* xr = x + (size_t)(n0 + rt * 16 + l15) * D_DIM;
        #pragma unroll
        for (int ks = 0; ks < 4; ks++) {
            const int k0 = ks * 32 + h * 8;
            float4 v0 = *(const float4*)(xr + k0);
            float4 v1 = *(const float4*)(xr + k0 + 4);
            float vv[8] = {v0.x, v0.y, v0.z, v0.w, v1.x, v1.y, v1.z, v1.w};
            s16x8 hi8, lo8;
            #pragma unroll
            for (int j = 0; j < 8; j++) {
                ushort hi = f2bf(vv[j]);
                hi8[j] = (short)hi;
                lo8[j] = (short)f2bf(vv[j] - bf2f(hi));
            }
            xh[rt][ks] = hi8;
            xl[rt][ks] = lo8;
        }
    }

    const f32x4 zz = {0.f, 0.f, 0.f, 0.f};
    f32x4 qacc[2][8];
    #pragma unroll
    for (int rt = 0; rt < 2; rt++)
        #pragma unroll
        for (int dt = 0; dt < 8; dt++) qacc[rt][dt] = zz;

    float S[2] = {0.f, 0.f}, T[2] = {0.f, 0.f}, Sg[2] = {0.f, 0.f};
    float bv1[2] = {-INFINITY, -INFINITY}, bv2[2] = {-INFINITY, -INFINITY};
    int bi1[2] = {M_EMB, M_EMB}, bi2[2] = {M_EMB, M_EMB};

    const float* urow[2] = {u + (size_t)(n0 + l15) * M_EMB,
                            u + (size_t)(n0 + 16 + l15) * M_EMB};
    const float EPS = 1.1920929e-07f, OME = 0.99999988f;

    #pragma unroll 1
    for (int mc = w * 8; mc < w * 8 + 8; mc++) {
        const int mb = mc * 32;
        // hoist the HBM-latency u loads for this whole chunk ahead of the MFMAs
        float4 uvv[2][2];
        #pragma unroll
        for (int t2 = 0; t2 < 2; t2++)
            #pragma unroll
            for (int rt = 0; rt < 2; rt++)
                uvv[t2][rt] = *(const float4*)(urow[rt] + mb + t2 * 16 + h * 4);
        #pragma unroll
        for (int t2 = 0; t2 < 2; t2++) {
            const int msub = mb + t2 * 16;
            // A-fragments: E rows (msub + l15), shared across both n-tiles
            s16x8 ah[4], al[4];
            #pragma unroll
            for (int ks = 0; ks < 4; ks++) {
                const int bidx = (msub + l15) * 16 + ks * 4 + h;
                ah[ks] = EH[bidx];
                al[ks] = EL[bidx];
            }
            // scores: D[m = 4h+j][n = l15] per rt, 3-way bf16 split
            f32x4 sc[2];
            #pragma unroll
            for (int rt = 0; rt < 2; rt++) {
                f32x4 aa = zz, ab = zz, ac = zz;
                #pragma unroll
                for (int ks = 0; ks < 4; ks++) {
                    aa = mfma_k32(ah[ks], xh[rt][ks], aa);
                    ab = mfma_k32(al[ks], xh[rt][ks], ab);
                    ac = mfma_k32(ah[ks], xl[rt][ks], ac);
                }
                #pragma unroll
                for (int j = 0; j < 4; j++) sc[rt][j] = aa[j] + ab[j] + ac[j];
            }
            const float4 e2v = *(const float4*)(e2g + msub + h * 4);
            #pragma unroll
            for (int rt = 0; rt < 2; rt++) {
                const float uu[4] = {uvv[t2][rt].x, uvv[t2][rt].y, uvv[t2][rt].z, uvv[t2][rt].w};
                const float ee[4] = {e2v.x, e2v.y, e2v.z, e2v.w};
                ushort pb[4];
                #pragma unroll
                for (int j = 0; j < 4; j++) {
                    const int m = msub + h * 4 + j;
                    const float v = prec * sc[rt][j] - hp * ee[j];
                    // top-2 (ascending m within lane, keep-first ties)
                    if (v > bv1[rt]) {
                        bv2[rt] = bv1[rt]; bi2[rt] = bi1[rt];
                        bv1[rt] = v; bi1[rt] = m;
                    } else if (v > bv2[rt]) {
                        bv2[rt] = v; bi2[rt] = m;
                    }
                    // entropy sums (no max shift needed: |v| <~ 40)
                    const float e = __expf(v);
                    S[rt] += e; T[rt] += e * v;
                    // gumbel: p~ = exp(v + g) = e / (-log u); series for u->1
                    const float uc = fminf(fmaxf(uu[j], EPS), OME);
                    const float d1 = 1.0f - uc;
                    const float Lser = d1 * (1.0f + d1 * (0.5f + d1 * (0.33333334f + d1 * 0.25f)));
                    const float Lnat = -__logf(uc);
                    const float L = (d1 < 0.03125f) ? Lser : Lnat;
                    const float pt = e * __builtin_amdgcn_rcpf(L);
                    Sg[rt] += pt;
                    pb[j] = f2bf(pt);
                }
                // PV: p~ tile is already in mfma_16x16x16 A-layout (row n=l15, k=4h+j)
                s16x4 pa;
                pa[0] = (short)pb[0]; pa[1] = (short)pb[1];
                pa[2] = (short)pb[2]; pa[3] = (short)pb[3];
                const int bbase = l15 * 256 + (mb >> 2) + t2 * 4 + h;
                #pragma unroll
                for (int dt = 0; dt < 8; dt++) {
                    const int bidx = dt * 4096 + bbase;
                    qacc[rt][dt] = mfma_k16(pa, TH4[bidx], qacc[rt][dt]);
                    qacc[rt][dt] = mfma_k16(pa, TL4[bidx], qacc[rt][dt]);
                }
            }
        }
    }

    // ---- in-wave reduce across h-group (lanes l, l^16, l^32, l^48) ----
    #pragma unroll
    for (int rt = 0; rt < 2; rt++) {
        #pragma unroll
        for (int off = 16; off <= 32; off <<= 1) {
            S[rt] += __shfl_xor(S[rt], off);
            T[rt] += __shfl_xor(T[rt], off);
            Sg[rt] += __shfl_xor(Sg[rt], off);
            const float ov1 = __shfl_xor(bv1[rt], off); const int oi1 = __shfl_xor(bi1[rt], off);
            const float ov2 = __shfl_xor(bv2[rt], off); const int oi2 = __shfl_xor(bi2[rt], off);
            if (ov1 > bv1[rt] || (ov1 == bv1[rt] && oi1 < bi1[rt])) {
                if (bv1[rt] > ov2 || (bv1[rt] == ov2 && bi1[rt] < oi2)) { bv2[rt] = bv1[rt]; bi2[rt] = bi1[rt]; }
                else { bv2[rt] = ov2; bi2[rt] = oi2; }
                bv1[rt] = ov1; bi1[rt] = oi1;
            } else if (ov1 > bv2[rt] || (ov1 == bv2[rt] && oi1 < bi2[rt])) {
                bv2[rt] = ov1; bi2[rt] = oi1;
            }
        }
    }

    // ---- publish per-wave partial stats ----
    if (lane < 16) {
        #pragma unroll
        for (int rt = 0; rt < 2; rt++) {
            lds_S[w][rt][lane] = S[rt];
            lds_T[w][rt][lane] = T[rt];
            lds_Sg[w][rt][lane] = Sg[rt];
            lds_b1[w][rt][lane] = bv1[rt]; lds_i1[w][rt][lane] = bi1[rt];
            lds_b2[w][rt][lane] = bv2[rt]; lds_i2[w][rt][lane] = bi2[rt];
        }
    }
    __syncthreads();

    // ---- merge stats across the 4 m-quarters (every lane, row = l15) ----
    float Sm[2], Tm[2], Sgm[2];
    int I1[2], I2[2];
    #pragma unroll
    for (int rt = 0; rt < 2; rt++) {
        float sS = 0.f, sT = 0.f, sG = 0.f, b1 = -INFINITY, b2 = -INFINITY;
        int i1 = M_EMB, i2 = M_EMB;
        #pragma unroll
        for (int pw = 0; pw < 4; pw++) {
            sS += lds_S[pw][rt][l15];
            sT += lds_T[pw][rt][l15];
            sG += lds_Sg[pw][rt][l15];
            const float v1 = lds_b1[pw][rt][l15]; const int ii1 = lds_i1[pw][rt][l15];
            const float v2 = lds_b2[pw][rt][l15]; const int ii2 = lds_i2[pw][rt][l15];
            if (v1 > b1 || (v1 == b1 && ii1 < i1)) { b2 = b1; i2 = i1; b1 = v1; i1 = ii1; }
            else if (v1 > b2 || (v1 == b2 && ii1 < i2)) { b2 = v1; i2 = ii1; }
            if (v2 > b2 || (v2 == b2 && ii2 < i2)) { b2 = v2; i2 = ii2; }
        }
        Sm[rt] = sS; Tm[rt] = sT; Sgm[rt] = sG;
        I1[rt] = i1; I2[rt] = i2;
    }
    float invv[2][4];
    #pragma unroll
    for (int rt = 0; rt < 2; rt++)
        #pragma unroll
        for (int j = 0; j < 4; j++)
            invv[rt][j] = 1.0f / __shfl(Sgm[rt], 4 * h + j);

    // ---- role work: waves 0/1 recheck rt 0/1; wave 2 entropy ----
    if (w < 2) {
        const int rt = w;
        const float* xr = x + (size_t)(n0 + rt * 16 + l15) * D_DIM + h * 32;
        const float* ea = emb + (size_t)I1[rt] * D_DIM + h * 32;
        const float* eb = emb + (size_t)I2[rt] * D_DIM + h * 32;
        float s1 = 0.f, s2 = 0.f;
        #pragma unroll
        for (int i = 0; i < 8; i++) {
            const float4 xv = ((const float4*)xr)[i];
            const float4 av = ((const float4*)ea)[i];
            const float4 bb = ((const float4*)eb)[i];
            s1 += xv.x * av.x + xv.y * av.y + xv.z * av.z + xv.w * av.w;
            s2 += xv.x * bb.x + xv.y * bb.y + xv.z * bb.z + xv.w * bb.w;
        }
        #pragma unroll
        for (int off = 16; off <= 32; off <<= 1) {
            s1 += __shfl_xor(s1, off);
            s2 += __shfl_xor(s2, off);
        }
        const float g1 = prec * s1 - hp * e2g[I1[rt]];
        const float g2 = prec * s2 - hp * e2g[I2[rt]];
        const int win = (g2 > g1 || (g2 == g1 && I2[rt] < I1[rt])) ? I2[rt] : I1[rt];
        if (lane < 16) {
            out[(size_t)N_TOK * D_DIM + n0 + rt * 16 + lane] = (float)win;
            atomicAdd(&cnt[win], 1);
        }
    } else if (w == 2) {
        float ent = (Tm[0] / Sm[0] - __logf(Sm[0])) + (Tm[1] / Sm[1] - __logf(Sm[1]));
        #pragma unroll
        for (int off = 1; off <= 8; off <<= 1) ent += __shfl_xor(ent, off);
        if (lane == 0) atomicAdd(ws_ent, ent);
    }

    // ---- merge qacc partials in two 32 KB LDS chunks; each wave owns 2 dt ----
    float sslw = 0.f;
    #pragma unroll 1
    for (int rtc = 0; rtc < 2; rtc++) {
        if (rtc) __syncthreads();        // prev chunk fully read before overwrite
        #pragma unroll
        for (int dt = 0; dt < 8; dt++)
            #pragma unroll
            for (int j = 0; j < 4; j++)
                lds_q[dt * 4 + j][w][lane] = qacc[rtc][dt][j];
        __syncthreads();
        #pragma unroll
        for (int dp = 0; dp < 2; dp++) {
            const int dt = 2 * w + dp;
            #pragma unroll
            for (int j = 0; j < 4; j++) {
                const float qm = lds_q[dt * 4 + j][0][lane] + lds_q[dt * 4 + j][1][lane]
                               + lds_q[dt * 4 + j][2][lane] + lds_q[dt * 4 + j][3][lane];
                const float q = qm * invv[rtc][j];
                const int n = n0 + rtc * 16 + 4 * h + j;
                const int d = dt * 16 + l15;
                out[(size_t)n * D_DIM + d] = q;
                const float df = x[(size_t)n * D_DIM + d] - q;
                sslw += df * df;
            }
        }
    }
    #pragma unroll
    for (int off = 1; off <= 32; off <<= 1) sslw += __shfl_xor(sslw, off);
    if (lane == 0) atomicAdd(ws_ss, sslw);

    // ---- last-block finalization (folds old k_final; saves one launch) ----
    __syncthreads();                     // all block atomics issued & drained
    if (t == 0) {
        const int prev = __hip_atomic_fetch_add((int*)(ws + WS_DONE), 1,
                            __ATOMIC_ACQ_REL, __HIP_MEMORY_SCOPE_AGENT);
        last_flag = (prev == (int)gridDim.x - 1);
    }
    __syncthreads();
    if (last_flag) {
        float s = 0.f;
        for (int i = t; i < M_EMB; i += 256) {
            const int c = __hip_atomic_load(&cnt[i], __ATOMIC_RELAXED,
                                            __HIP_MEMORY_SCOPE_AGENT);
            const float avg = (float)c * (1.f / N_TOK);
            s += avg * logf(avg + 1e-10f);
        }
        #pragma unroll
        for (int off = 32; off >= 1; off >>= 1) s += __shfl_down(s, off);
        if ((t & 63) == 0) fin[t >> 6] = s;
        __syncthreads();
        if (t == 0) {
            const float tot = fin[0] + fin[1] + fin[2] + fin[3];
            const float perp = expf(-tot);
            const float ssv = __hip_atomic_load(ws_ss, __ATOMIC_RELAXED,
                                                __HIP_MEMORY_SCOPE_AGENT);
            const float env = __hip_atomic_load(ws_ent, __ATOMIC_RELAXED,
                                                __HIP_MEMORY_SCOPE_AGENT);
            out[(size_t)N_TOK * D_DIM + N_TOK] = hp * ssv + env;
            out[(size_t)N_TOK * D_DIM + N_TOK + 1] = perp;
        }
    }
}

extern "C" void kernel_launch(void* const* d_in, const int* in_sizes, int n_in,
                              void* d_out, int out_size, void* d_ws, size_t ws_size,
                              hipStream_t stream) {
    const float* x   = (const float*)d_in[0];
    const float* emb = (const float*)d_in[1];
    const float* lvq = (const float*)d_in[2];
    const float* u   = (const float*)d_in[3];
    float* out = (float*)d_out;
    char* ws = (char*)d_ws;
    k_prep<<<dim3(M_EMB / 16), dim3(256), 0, stream>>>(emb, ws);
    k_main<<<dim3(N_TOK / 32), dim3(256), 0, stream>>>(x, emb, lvq, u, out, ws);
}

// Round 9
// 596.929 us; speedup vs baseline: 2.1016x; 1.0010x over previous
//
#include <hip/hip_runtime.h>
#include <math.h>

#define N_TOK 32768
#define M_EMB 1024
#define D_DIM 128

// workspace layout (bytes)
#define WS_EH  0                        // bf16 e_hi[1024][128]   (256 KB)
#define WS_EL  262144                   // bf16 e_lo[1024][128]   (256 KB)
#define WS_TH  524288                   // bf16 et_hi[128][1024]  (256 KB)
#define WS_TL  786432                   // bf16 et_lo[128][1024]  (256 KB)
#define WS_E2  1048576                  // float e2[1024]
#define WS_CNT (WS_E2 + 4096)           // int counts[1024]
#define WS_SS  (WS_CNT + 4096)          // float sum((x-q)^2)
#define WS_ENT (WS_SS + 4)              // float sum(p*logp)
#define WS_DONE (WS_ENT + 4)            // int: blocks-finished counter

typedef float  f32x4  __attribute__((ext_vector_type(4)));
typedef short  s16x8  __attribute__((ext_vector_type(8)));
typedef short  s16x4  __attribute__((ext_vector_type(4)));
typedef __bf16 bf16x8 __attribute__((ext_vector_type(8)));

__device__ __forceinline__ ushort f2bf(float f) {
    unsigned x = __float_as_uint(f);
    unsigned r = (x + 0x7fffu + ((x >> 16) & 1u)) >> 16;
    return (ushort)r;
}
__device__ __forceinline__ float bf2f(ushort h) {
    return __uint_as_float(((unsigned)h) << 16);
}
__device__ __forceinline__ f32x4 mfma_k32(s16x8 a, s16x8 b, f32x4 c) {
    return __builtin_amdgcn_mfma_f32_16x16x32_bf16(
        __builtin_bit_cast(bf16x8, a), __builtin_bit_cast(bf16x8, b), c, 0, 0, 0);
}
__device__ __forceinline__ f32x4 mfma_k16(s16x4 a, s16x4 b, f32x4 c) {
#if __has_builtin(__builtin_amdgcn_mfma_f32_16x16x16bf16_1k)
    return __builtin_amdgcn_mfma_f32_16x16x16bf16_1k(a, b, c, 0, 0, 0);
#else
    asm("v_mfma_f32_16x16x16_bf16 %0, %1, %2, %0" : "+v"(c) : "v"(a), "v"(b));
    return c;
#endif
}

// Convert embedding to bf16 hi/lo in row-major and transposed layouts; e2; zero accums.
__global__ void k_prep(const float* __restrict__ emb, char* ws) {
    __shared__ ushort th_s[16][128];
    __shared__ ushort tl_s[16][128];
    if (blockIdx.x == 0) {
        int* cnt = (int*)(ws + WS_CNT);
        for (int i = threadIdx.x; i < M_EMB; i += 256) cnt[i] = 0;
        if (threadIdx.x == 0) {
            *(float*)(ws + WS_SS) = 0.f;
            *(float*)(ws + WS_ENT) = 0.f;
            *(int*)(ws + WS_DONE) = 0;
        }
    }
    ushort* eh = (ushort*)(ws + WS_EH);
    ushort* el = (ushort*)(ws + WS_EL);
    ushort* th = (ushort*)(ws + WS_TH);
    ushort* tl = (ushort*)(ws + WS_TL);
    float* e2 = (float*)(ws + WS_E2);
    const int m0 = blockIdx.x * 16;
    const int t = threadIdx.x;
    #pragma unroll
    for (int ii = 0; ii < 8; ii++) {
        int idx = t + ii * 256;          // 0..2047
        int mi = idx >> 7, k = idx & 127;
        float v = emb[(size_t)(m0 + mi) * D_DIM + k];
        ushort hi = f2bf(v);
        ushort lo = f2bf(v - bf2f(hi));
        eh[(size_t)(m0 + mi) * D_DIM + k] = hi;
        el[(size_t)(m0 + mi) * D_DIM + k] = lo;
        th_s[mi][k] = hi;
        tl_s[mi][k] = lo;
    }
    __syncthreads();
    {
        int k = t >> 1, half = t & 1;
        s16x8 vh, vl;
        #pragma unroll
        for (int j = 0; j < 8; j++) {
            vh[j] = (short)th_s[half * 8 + j][k];
            vl[j] = (short)tl_s[half * 8 + j][k];
        }
        *(s16x8*)(th + (size_t)k * M_EMB + m0 + half * 8) = vh;
        *(s16x8*)(tl + (size_t)k * M_EMB + m0 + half * 8) = vl;
    }
    if (t < 16) {
        float s = 0.f;
        const float* er = emb + (size_t)(m0 + t) * D_DIM;
        #pragma unroll 4
        for (int k = 0; k < 128; k++) s += er[k] * er[k];
        e2[m0 + t] = s;
    }
}

// Flash-style fused kernel, m-split 4 ways across the block's 4 waves.
// Block = one 32-row tile; wave w streams m in [256w, 256w+256).
// Main loop has NO barriers; partial qacc/stats merged via LDS at the end.
// REGISTER BUDGET (round-8 lesson): live state ~200 VGPR. launch_bounds(256,2)
// only sets MIN waves/EU; the allocator still targeted 4 waves/SIMD (128 VGPR)
// and spilled ~70 regs -> 0.5 GB scratch round-trip (FETCH 468/WRITE 253 MB).
// amdgpu_waves_per_eu(2,2) sets MAX=2 too -> allocator may use up to 256 VGPR
// -> no spill at 2 waves/SIMD.
__global__ __attribute__((amdgpu_flat_work_group_size(256, 256),
                          amdgpu_waves_per_eu(2, 2)))
void k_main(
    const float* __restrict__ x, const float* __restrict__ emb,
    const float* __restrict__ lvq, const float* __restrict__ u,
    float* __restrict__ out, char* __restrict__ ws)
{
    __shared__ float lds_q[32][4][64];                    // 32 KB, [idx][wave][lane]
    __shared__ float lds_S[4][2][16], lds_T[4][2][16], lds_Sg[4][2][16];
    __shared__ float lds_b1[4][2][16], lds_b2[4][2][16];
    __shared__ int   lds_i1[4][2][16], lds_i2[4][2][16];
    __shared__ int   last_flag;
    __shared__ float fin[4];

    const int t = threadIdx.x;
    const int w = t >> 6;            // wave 0..3 -> m-quarter
    const int lane = t & 63;
    const int l15 = lane & 15;
    const int h = lane >> 4;
    const int n0 = blockIdx.x * 32;

    const float* e2g = (const float*)(ws + WS_E2);
    int* cnt = (int*)(ws + WS_CNT);
    float* ws_ss = (float*)(ws + WS_SS);
    float* ws_ent = (float*)(ws + WS_ENT);
    const s16x8* EH = (const s16x8*)(ws + WS_EH);
    const s16x8* EL = (const s16x8*)(ws + WS_EL);
    const s16x4* TH4 = (const s16x4*)(ws + WS_TH);
    const s16x4* TL4 = (const s16x4*)(ws + WS_TL);

    const float prec = expf(-lvq[0]);
    const float hp = 0.5f * prec;

    // ---- x B-fragments (rows n0 + rt*16 + l15), split hi/lo ----
    s16x8 xh[2][4], xl[2][4];
    #pragma unroll
    for (int rt = 0; rt < 2; rt++) {
        const float* xr = x + (size_t)(n0 + rt * 16 + l15) * D_DIM;
        #pragma unroll
        for (int ks = 0; ks < 4; ks++) {
            const int k0 = ks * 32 + h * 8;
            float4 v0 = *(const float4*)(xr + k0);
            float4 v1 = *(const float4*)(xr + k0 + 4);
            float vv[8] = {v0.x, v0.y, v0.z, v0.w, v1.x, v1.y, v1.z, v1.w};
            s16x8 hi8, lo8;
            #pragma unroll
            for (int j = 0; j < 8; j++) {
                ushort hi = f2bf(vv[j]);
                hi8[j] = (short)hi;
                lo8[j] = (short)f2bf(vv[j] - bf2f(hi));
            }
            xh[rt][ks] = hi8;
            xl[rt][ks] = lo8;
        }
    }

    const f32x4 zz = {0.f, 0.f, 0.f, 0.f};
    f32x4 qacc[2][8];
    #pragma unroll
    for (int rt = 0; rt < 2; rt++)
        #pragma unroll
        for (int dt = 0; dt < 8; dt++) qacc[rt][dt] = zz;

    float S[2] = {0.f, 0.f}, T[2] = {0.f, 0.f}, Sg[2] = {0.f, 0.f};
    float bv1[2] = {-INFINITY, -INFINITY}, bv2[2] = {-INFINITY, -INFINITY};
    int bi1[2] = {M_EMB, M_EMB}, bi2[2] = {M_EMB, M_EMB};

    const float* urow[2] = {u + (size_t)(n0 + l15) * M_EMB,
                            u + (size_t)(n0 + 16 + l15) * M_EMB};
    const float EPS = 1.1920929e-07f, OME = 0.99999988f;

    #pragma unroll 1
    for (int mc = w * 8; mc < w * 8 + 8; mc++) {
        const int mb = mc * 32;
        // hoist the HBM-latency u loads for this whole chunk ahead of the MFMAs
        float4 uvv[2][2];
        #pragma unroll
        for (int t2 = 0; t2 < 2; t2++)
            #pragma unroll
            for (int rt = 0; rt < 2; rt++)
                uvv[t2][rt] = *(const float4*)(urow[rt] + mb + t2 * 16 + h * 4);
        #pragma unroll
        for (int t2 = 0; t2 < 2; t2++) {
            const int msub = mb + t2 * 16;
            // A-fragments: E rows (msub + l15), shared across both n-tiles
            s16x8 ah[4], al[4];
            #pragma unroll
            for (int ks = 0; ks < 4; ks++) {
                const int bidx = (msub + l15) * 16 + ks * 4 + h;
                ah[ks] = EH[bidx];
                al[ks] = EL[bidx];
            }
            // scores: D[m = 4h+j][n = l15] per rt, 3-way bf16 split
            f32x4 sc[2];
            #pragma unroll
            for (int rt = 0; rt < 2; rt++) {
                f32x4 aa = zz, ab = zz, ac = zz;
                #pragma unroll
                for (int ks = 0; ks < 4; ks++) {
                    aa = mfma_k32(ah[ks], xh[rt][ks], aa);
                    ab = mfma_k32(al[ks], xh[rt][ks], ab);
                    ac = mfma_k32(ah[ks], xl[rt][ks], ac);
                }
                #pragma unroll
                for (int j = 0; j < 4; j++) sc[rt][j] = aa[j] + ab[j] + ac[j];
            }
            const float4 e2v = *(const float4*)(e2g + msub + h * 4);
            #pragma unroll
            for (int rt = 0; rt < 2; rt++) {
                const float uu[4] = {uvv[t2][rt].x, uvv[t2][rt].y, uvv[t2][rt].z, uvv[t2][rt].w};
                const float ee[4] = {e2v.x, e2v.y, e2v.z, e2v.w};
                ushort pb[4];
                #pragma unroll
                for (int j = 0; j < 4; j++) {
                    const int m = msub + h * 4 + j;
                    const float v = prec * sc[rt][j] - hp * ee[j];
                    // top-2 (ascending m within lane, keep-first ties)
                    if (v > bv1[rt]) {
                        bv2[rt] = bv1[rt]; bi2[rt] = bi1[rt];
                        bv1[rt] = v; bi1[rt] = m;
                    } else if (v > bv2[rt]) {
                        bv2[rt] = v; bi2[rt] = m;
                    }
                    // entropy sums (no max shift needed: |v| <~ 40)
                    const float e = __expf(v);
                    S[rt] += e; T[rt] += e * v;
                    // gumbel: p~ = exp(v + g) = e / (-log u); series for u->1
                    const float uc = fminf(fmaxf(uu[j], EPS), OME);
                    const float d1 = 1.0f - uc;
                    const float Lser = d1 * (1.0f + d1 * (0.5f + d1 * (0.33333334f + d1 * 0.25f)));
                    const float Lnat = -__logf(uc);
                    const float L = (d1 < 0.03125f) ? Lser : Lnat;
                    const float pt = e * __builtin_amdgcn_rcpf(L);
                    Sg[rt] += pt;
                    pb[j] = f2bf(pt);
                }
                // PV: p~ tile is already in mfma_16x16x16 A-layout (row n=l15, k=4h+j)
                s16x4 pa;
                pa[0] = (short)pb[0]; pa[1] = (short)pb[1];
                pa[2] = (short)pb[2]; pa[3] = (short)pb[3];
                const int bbase = l15 * 256 + (mb >> 2) + t2 * 4 + h;
                #pragma unroll
                for (int dt = 0; dt < 8; dt++) {
                    const int bidx = dt * 4096 + bbase;
                    qacc[rt][dt] = mfma_k16(pa, TH4[bidx], qacc[rt][dt]);
                    qacc[rt][dt] = mfma_k16(pa, TL4[bidx], qacc[rt][dt]);
                }
            }
        }
    }

    // ---- in-wave reduce across h-group (lanes l, l^16, l^32, l^48) ----
    #pragma unroll
    for (int rt = 0; rt < 2; rt++) {
        #pragma unroll
        for (int off = 16; off <= 32; off <<= 1) {
            S[rt] += __shfl_xor(S[rt], off);
            T[rt] += __shfl_xor(T[rt], off);
            Sg[rt] += __shfl_xor(Sg[rt], off);
            const float ov1 = __shfl_xor(bv1[rt], off); const int oi1 = __shfl_xor(bi1[rt], off);
            const float ov2 = __shfl_xor(bv2[rt], off); const int oi2 = __shfl_xor(bi2[rt], off);
            if (ov1 > bv1[rt] || (ov1 == bv1[rt] && oi1 < bi1[rt])) {
                if (bv1[rt] > ov2 || (bv1[rt] == ov2 && bi1[rt] < oi2)) { bv2[rt] = bv1[rt]; bi2[rt] = bi1[rt]; }
                else { bv2[rt] = ov2; bi2[rt] = oi2; }
                bv1[rt] = ov1; bi1[rt] = oi1;
            } else if (ov1 > bv2[rt] || (ov1 == bv2[rt] && oi1 < bi2[rt])) {
                bv2[rt] = ov1; bi2[rt] = oi1;
            }
        }
    }

    // ---- publish per-wave partial stats ----
    if (lane < 16) {
        #pragma unroll
        for (int rt = 0; rt < 2; rt++) {
            lds_S[w][rt][lane] = S[rt];
            lds_T[w][rt][lane] = T[rt];
            lds_Sg[w][rt][lane] = Sg[rt];
            lds_b1[w][rt][lane] = bv1[rt]; lds_i1[w][rt][lane] = bi1[rt];
            lds_b2[w][rt][lane] = bv2[rt]; lds_i2[w][rt][lane] = bi2[rt];
        }
    }
    __syncthreads();

    // ---- merge stats across the 4 m-quarters (every lane, row = l15) ----
    float Sm[2], Tm[2], Sgm[2];
    int I1[2], I2[2];
    #pragma unroll
    for (int rt = 0; rt < 2; rt++) {
        float sS = 0.f, sT = 0.f, sG = 0.f, b1 = -INFINITY, b2 = -INFINITY;
        int i1 = M_EMB, i2 = M_EMB;
        #pragma unroll
        for (int pw = 0; pw < 4; pw++) {
            sS += lds_S[pw][rt][l15];
            sT += lds_T[pw][rt][l15];
            sG += lds_Sg[pw][rt][l15];
            const float v1 = lds_b1[pw][rt][l15]; const int ii1 = lds_i1[pw][rt][l15];
            const float v2 = lds_b2[pw][rt][l15]; const int ii2 = lds_i2[pw][rt][l15];
            if (v1 > b1 || (v1 == b1 && ii1 < i1)) { b2 = b1; i2 = i1; b1 = v1; i1 = ii1; }
            else if (v1 > b2 || (v1 == b2 && ii1 < i2)) { b2 = v1; i2 = ii1; }
            if (v2 > b2 || (v2 == b2 && ii2 < i2)) { b2 = v2; i2 = ii2; }
        }
        Sm[rt] = sS; Tm[rt] = sT; Sgm[rt] = sG;
        I1[rt] = i1; I2[rt] = i2;
    }
    float invv[2][4];
    #pragma unroll
    for (int rt = 0; rt < 2; rt++)
        #pragma unroll
        for (int j = 0; j < 4; j++)
            invv[rt][j] = 1.0f / __shfl(Sgm[rt], 4 * h + j);

    // ---- role work: waves 0/1 recheck rt 0/1; wave 2 entropy ----
    if (w < 2) {
        const int rt = w;
        const float* xr = x + (size_t)(n0 + rt * 16 + l15) * D_DIM + h * 32;
        const float* ea = emb + (size_t)I1[rt] * D_DIM + h * 32;
        const float* eb = emb + (size_t)I2[rt] * D_DIM + h * 32;
        float s1 = 0.f, s2 = 0.f;
        #pragma unroll
        for (int i = 0; i < 8; i++) {
            const float4 xv = ((const float4*)xr)[i];
            const float4 av = ((const float4*)ea)[i];
            const float4 bb = ((const float4*)eb)[i];
            s1 += xv.x * av.x + xv.y * av.y + xv.z * av.z + xv.w * av.w;
            s2 += xv.x * bb.x + xv.y * bb.y + xv.z * bb.z + xv.w * bb.w;
        }
        #pragma unroll
        for (int off = 16; off <= 32; off <<= 1) {
            s1 += __shfl_xor(s1, off);
            s2 += __shfl_xor(s2, off);
        }
        const float g1 = prec * s1 - hp * e2g[I1[rt]];
        const float g2 = prec * s2 - hp * e2g[I2[rt]];
        const int win = (g2 > g1 || (g2 == g1 && I2[rt] < I1[rt])) ? I2[rt] : I1[rt];
        if (lane < 16) {
            out[(size_t)N_TOK * D_DIM + n0 + rt * 16 + lane] = (float)win;
            atomicAdd(&cnt[win], 1);
        }
    } else if (w == 2) {
        float ent = (Tm[0] / Sm[0] - __logf(Sm[0])) + (Tm[1] / Sm[1] - __logf(Sm[1]));
        #pragma unroll
        for (int off = 1; off <= 8; off <<= 1) ent += __shfl_xor(ent, off);
        if (lane == 0) atomicAdd(ws_ent, ent);
    }

    // ---- merge qacc partials in two 32 KB LDS chunks; each wave owns 2 dt ----
    float sslw = 0.f;
    #pragma unroll 1
    for (int rtc = 0; rtc < 2; rtc++) {
        if (rtc) __syncthreads();        // prev chunk fully read before overwrite
        #pragma unroll
        for (int dt = 0; dt < 8; dt++)
            #pragma unroll
            for (int j = 0; j < 4; j++)
                lds_q[dt * 4 + j][w][lane] = qacc[rtc][dt][j];
        __syncthreads();
        #pragma unroll
        for (int dp = 0; dp < 2; dp++) {
            const int dt = 2 * w + dp;
            #pragma unroll
            for (int j = 0; j < 4; j++) {
                const float qm = lds_q[dt * 4 + j][0][lane] + lds_q[dt * 4 + j][1][lane]
                               + lds_q[dt * 4 + j][2][lane] + lds_q[dt * 4 + j][3][lane];
                const float q = qm * invv[rtc][j];
                const int n = n0 + rtc * 16 + 4 * h + j;
                const int d = dt * 16 + l15;
                out[(size_t)n * D_DIM + d] = q;
                const float df = x[(size_t)n * D_DIM + d] - q;
                sslw += df * df;
            }
        }
    }
    #pragma unroll
    for (int off = 1; off <= 32; off <<= 1) sslw += __shfl_xor(sslw, off);
    if (lane == 0) atomicAdd(ws_ss, sslw);

    // ---- last-block finalization (folds old k_final; saves one launch) ----
    __syncthreads();                     // all block atomics issued & drained
    if (t == 0) {
        const int prev = __hip_atomic_fetch_add((int*)(ws + WS_DONE), 1,
                            __ATOMIC_ACQ_REL, __HIP_MEMORY_SCOPE_AGENT);
        last_flag = (prev == (int)gridDim.x - 1);
    }
    __syncthreads();
    if (last_flag) {
        float s = 0.f;
        for (int i = t; i < M_EMB; i += 256) {
            const int c = __hip_atomic_load(&cnt[i], __ATOMIC_RELAXED,
                                            __HIP_MEMORY_SCOPE_AGENT);
            const float avg = (float)c * (1.f / N_TOK);
            s += avg * logf(avg + 1e-10f);
        }
        #pragma unroll
        for (int off = 32; off >= 1; off >>= 1) s += __shfl_down(s, off);
        if ((t & 63) == 0) fin[t >> 6] = s;
        __syncthreads();
        if (t == 0) {
            const float tot = fin[0] + fin[1] + fin[2] + fin[3];
            const float perp = expf(-tot);
            const float ssv = __hip_atomic_load(ws_ss, __ATOMIC_RELAXED,
                                                __HIP_MEMORY_SCOPE_AGENT);
            const float env = __hip_atomic_load(ws_ent, __ATOMIC_RELAXED,
                                                __HIP_MEMORY_SCOPE_AGENT);
            out[(size_t)N_TOK * D_DIM + N_TOK] = hp * ssv + env;
            out[(size_t)N_TOK * D_DIM + N_TOK + 1] = perp;
        }
    }
}

extern "C" void kernel_launch(void* const* d_in, const int* in_sizes, int n_in,
                              void* d_out, int out_size, void* d_ws, size_t ws_size,
                              hipStream_t stream) {
    const float* x   = (const float*)d_in[0];
    const float* emb = (const float*)d_in[1];
    const float* lvq = (const float*)d_in[2];
    const float* u   = (const float*)d_in[3];
    float* out = (float*)d_out;
    char* ws = (char*)d_ws;
    k_prep<<<dim3(M_EMB / 16), dim3(256), 0, stream>>>(emb, ws);
    k_main<<<dim3(N_TOK / 32), dim3(256), 0, stream>>>(x, emb, lvq, u, out, ws);
}

// Round 13
// 582.179 us; speedup vs baseline: 2.1549x; 1.0253x over previous
//
#include <hip/hip_runtime.h>
#include <math.h>

#define N_TOK 32768
#define M_EMB 1024
#define D_DIM 128

// workspace layout (bytes)
#define WS_EH  0                        // bf16 e_hi[1024][128]   (256 KB)
#define WS_EL  262144                   // bf16 e_lo[1024][128]   (256 KB)
#define WS_TH  524288                   // bf16 et_hi[128][1024]  (256 KB)
#define WS_TL  786432                   // bf16 et_lo[128][1024]  (256 KB)
#define WS_E2  1048576                  // float e2[1024]
#define WS_CNT (WS_E2 + 4096)           // int counts[1024]
#define WS_SS  (WS_CNT + 4096)          // float sum((x-q)^2)
#define WS_ENT (WS_SS + 4)              // float sum(p*logp)
#define WS_DONE (WS_ENT + 4)            // int: blocks-finished counter

typedef float  f32x4  __attribute__((ext_vector_type(4)));
typedef short  s16x8  __attribute__((ext_vector_type(8)));
typedef short  s16x4  __attribute__((ext_vector_type(4)));
typedef __bf16 bf16x8 __attribute__((ext_vector_type(8)));

__device__ __forceinline__ ushort f2bf(float f) {
    unsigned x = __float_as_uint(f);
    unsigned r = (x + 0x7fffu + ((x >> 16) & 1u)) >> 16;
    return (ushort)r;
}
__device__ __forceinline__ float bf2f(ushort h) {
    return __uint_as_float(((unsigned)h) << 16);
}
__device__ __forceinline__ f32x4 mfma_k32(s16x8 a, s16x8 b, f32x4 c) {
    return __builtin_amdgcn_mfma_f32_16x16x32_bf16(
        __builtin_bit_cast(bf16x8, a), __builtin_bit_cast(bf16x8, b), c, 0, 0, 0);
}
__device__ __forceinline__ f32x4 mfma_k16(s16x4 a, s16x4 b, f32x4 c) {
#if __has_builtin(__builtin_amdgcn_mfma_f32_16x16x16bf16_1k)
    return __builtin_amdgcn_mfma_f32_16x16x16bf16_1k(a, b, c, 0, 0, 0);
#else
    asm("v_mfma_f32_16x16x16_bf16 %0, %1, %2, %0" : "+v"(c) : "v"(a), "v"(b));
    return c;
#endif
}

// Convert embedding to bf16 hi/lo in row-major and transposed layouts; e2; zero accums.
__global__ void k_prep(const float* __restrict__ emb, char* ws) {
    __shared__ ushort th_s[16][128];
    __shared__ ushort tl_s[16][128];
    if (blockIdx.x == 0) {
        int* cnt = (int*)(ws + WS_CNT);
        for (int i = threadIdx.x; i < M_EMB; i += 256) cnt[i] = 0;
        if (threadIdx.x == 0) {
            *(float*)(ws + WS_SS) = 0.f;
            *(float*)(ws + WS_ENT) = 0.f;
            *(int*)(ws + WS_DONE) = 0;
        }
    }
    ushort* eh = (ushort*)(ws + WS_EH);
    ushort* el = (ushort*)(ws + WS_EL);
    ushort* th = (ushort*)(ws + WS_TH);
    ushort* tl = (ushort*)(ws + WS_TL);
    float* e2 = (float*)(ws + WS_E2);
    const int m0 = blockIdx.x * 16;
    const int t = threadIdx.x;
    #pragma unroll
    for (int ii = 0; ii < 8; ii++) {
        int idx = t + ii * 256;          // 0..2047
        int mi = idx >> 7, k = idx & 127;
        float v = emb[(size_t)(m0 + mi) * D_DIM + k];
        ushort hi = f2bf(v);
        ushort lo = f2bf(v - bf2f(hi));
        eh[(size_t)(m0 + mi) * D_DIM + k] = hi;
        el[(size_t)(m0 + mi) * D_DIM + k] = lo;
        th_s[mi][k] = hi;
        tl_s[mi][k] = lo;
    }
    __syncthreads();
    {
        int k = t >> 1, half = t & 1;
        s16x8 vh, vl;
        #pragma unroll
        for (int j = 0; j < 8; j++) {
            vh[j] = (short)th_s[half * 8 + j][k];
            vl[j] = (short)tl_s[half * 8 + j][k];
        }
        *(s16x8*)(th + (size_t)k * M_EMB + m0 + half * 8) = vh;
        *(s16x8*)(tl + (size_t)k * M_EMB + m0 + half * 8) = vl;
    }
    if (t < 16) {
        float s = 0.f;
        const float* er = emb + (size_t)(m0 + t) * D_DIM;
        #pragma unroll 4
        for (int k = 0; k < 128; k++) s += er[k] * er[k];
        e2[m0 + t] = s;
    }
}

// Flash-style fused kernel: each wave independently owns 16 rows and streams
// the FULL m range. No inter-wave merging, no main-loop barriers, no LDS
// (except the tiny finalization scratch).
// REGISTER BUDGET (rounds 8/9 lesson): the allocator will NOT exceed 128 VGPR
// for this kernel -- it spills to fit (0.5 GB scratch traffic both rounds,
// attributes didn't move it). So the live set must be < 128 structurally:
// 16 rows/wave halves qacc (32) + x-frags (32); total live ~115 -> no spill.
__global__ __launch_bounds__(256, 2) void k_main(
    const float* __restrict__ x, const float* __restrict__ emb,
    const float* __restrict__ lvq, const float* __restrict__ u,
    float* __restrict__ out, char* __restrict__ ws)
{
    __shared__ int last_flag;
    __shared__ float fin[4];

    const int t = threadIdx.x;
    const int w = t >> 6;            // wave 0..3, each owns 16 rows
    const int lane = t & 63;
    const int l15 = lane & 15;
    const int h = lane >> 4;
    const int n0w = blockIdx.x * 64 + w * 16;   // this wave's row base

    const float* e2g = (const float*)(ws + WS_E2);
    int* cnt = (int*)(ws + WS_CNT);
    float* ws_ss = (float*)(ws + WS_SS);
    float* ws_ent = (float*)(ws + WS_ENT);
    const s16x8* EH = (const s16x8*)(ws + WS_EH);
    const s16x8* EL = (const s16x8*)(ws + WS_EL);
    const s16x4* TH4 = (const s16x4*)(ws + WS_TH);
    const s16x4* TL4 = (const s16x4*)(ws + WS_TL);

    const float prec = expf(-lvq[0]);
    const float hp = 0.5f * prec;

    // ---- x B-fragments (rows n0w + l15), split hi/lo ----
    s16x8 xh[4], xl[4];
    {
        const float* xr = x + (size_t)(n0w + l15) * D_DIM;
        #pragma unroll
        for (int ks = 0; ks < 4; ks++) {
            const int k0 = ks * 32 + h * 8;
            float4 v0 = *(const float4*)(xr + k0);
            float4 v1 = *(const float4*)(xr + k0 + 4);
            float vv[8] = {v0.x, v0.y, v0.z, v0.w, v1.x, v1.y, v1.z, v1.w};
            s16x8 hi8, lo8;
            #pragma unroll
            for (int j = 0; j < 8; j++) {
                ushort hi = f2bf(vv[j]);
                hi8[j] = (short)hi;
                lo8[j] = (short)f2bf(vv[j] - bf2f(hi));
            }
            xh[ks] = hi8;
            xl[ks] = lo8;
        }
    }

    const f32x4 zz = {0.f, 0.f, 0.f, 0.f};
    f32x4 qacc[8];
    #pragma unroll
    for (int dt = 0; dt < 8; dt++) qacc[dt] = zz;

    float S = 0.f, T = 0.f, Sg = 0.f;
    float bv1 = -INFINITY, bv2 = -INFINITY;
    int bi1 = M_EMB, bi2 = M_EMB;

    const float* urow = u + (size_t)(n0w + l15) * M_EMB;
    const float EPS = 1.1920929e-07f, OME = 0.99999988f;

    #pragma unroll 1
    for (int mc = 0; mc < 32; mc++) {
        const int mb = mc * 32;
        // hoist the HBM-latency u loads for this chunk ahead of the MFMAs
        float4 uvv[2];
        #pragma unroll
        for (int t2 = 0; t2 < 2; t2++)
            uvv[t2] = *(const float4*)(urow + mb + t2 * 16 + h * 4);
        #pragma unroll
        for (int t2 = 0; t2 < 2; t2++) {
            const int msub = mb + t2 * 16;
            // scores: D[m = 4h+j][n = l15], 3-way bf16 split
            f32x4 aa = zz, ab = zz, ac = zz;
            #pragma unroll
            for (int ks = 0; ks < 4; ks++) {
                const int bidx = (msub + l15) * 16 + ks * 4 + h;
                const s16x8 ah = EH[bidx];
                const s16x8 al = EL[bidx];
                aa = mfma_k32(ah, xh[ks], aa);
                ab = mfma_k32(al, xh[ks], ab);
                ac = mfma_k32(ah, xl[ks], ac);
            }
            const float4 e2v = *(const float4*)(e2g + msub + h * 4);
            const float uu[4] = {uvv[t2].x, uvv[t2].y, uvv[t2].z, uvv[t2].w};
            const float ee[4] = {e2v.x, e2v.y, e2v.z, e2v.w};
            ushort pb[4];
            #pragma unroll
            for (int j = 0; j < 4; j++) {
                const int m = msub + h * 4 + j;
                const float v = prec * (aa[j] + ab[j] + ac[j]) - hp * ee[j];
                // top-2 (ascending m within lane, keep-first ties)
                if (v > bv1) {
                    bv2 = bv1; bi2 = bi1;
                    bv1 = v; bi1 = m;
                } else if (v > bv2) {
                    bv2 = v; bi2 = m;
                }
                // entropy sums (no max shift needed: |v| <~ 40)
                const float e = __expf(v);
                S += e; T += e * v;
                // gumbel: p~ = exp(v + g) = e / (-log u); series for u->1
                const float uc = fminf(fmaxf(uu[j], EPS), OME);
                const float d1 = 1.0f - uc;
                const float Lser = d1 * (1.0f + d1 * (0.5f + d1 * (0.33333334f + d1 * 0.25f)));
                const float Lnat = -__logf(uc);
                const float L = (d1 < 0.03125f) ? Lser : Lnat;
                const float pt = e * __builtin_amdgcn_rcpf(L);
                Sg += pt;
                pb[j] = f2bf(pt);
            }
            // PV: p~ tile is already in mfma_16x16x16 A-layout (row n=l15, k=4h+j)
            s16x4 pa;
            pa[0] = (short)pb[0]; pa[1] = (short)pb[1];
            pa[2] = (short)pb[2]; pa[3] = (short)pb[3];
            const int bbase = l15 * 256 + (mb >> 2) + t2 * 4 + h;
            #pragma unroll
            for (int dt = 0; dt < 8; dt++) {
                const int bidx = dt * 4096 + bbase;
                qacc[dt] = mfma_k16(pa, TH4[bidx], qacc[dt]);
                qacc[dt] = mfma_k16(pa, TL4[bidx], qacc[dt]);
            }
        }
    }

    // ---- reduce per-row stats across h-group (lanes l, l^16, l^32, l^48) ----
    #pragma unroll
    for (int off = 16; off <= 32; off <<= 1) {
        S += __shfl_xor(S, off);
        T += __shfl_xor(T, off);
        Sg += __shfl_xor(Sg, off);
        const float ov1 = __shfl_xor(bv1, off); const int oi1 = __shfl_xor(bi1, off);
        const float ov2 = __shfl_xor(bv2, off); const int oi2 = __shfl_xor(bi2, off);
        if (ov1 > bv1 || (ov1 == bv1 && oi1 < bi1)) {
            if (bv1 > ov2 || (bv1 == ov2 && bi1 < oi2)) { bv2 = bv1; bi2 = bi1; }
            else { bv2 = ov2; bi2 = oi2; }
            bv1 = ov1; bi1 = oi1;
        } else if (ov1 > bv2 || (ov1 == bv2 && oi1 < bi2)) {
            bv2 = ov1; bi2 = oi1;
        }
    }
    float inv[4];
    #pragma unroll
    for (int j = 0; j < 4; j++)
        inv[j] = 1.0f / __shfl(Sg, 4 * h + j);

    // ---- entropy: every lane holds its row's S,T (x4 dup); 16-lane sum ----
    {
        float ent = T / S - __logf(S);
        #pragma unroll
        for (int off = 1; off <= 8; off <<= 1) ent += __shfl_xor(ent, off);
        if (lane == 0) atomicAdd(ws_ent, ent);
    }

    // ---- exact fp32 recheck of top-2 candidates; write indices ----
    {
        const float* xr = x + (size_t)(n0w + l15) * D_DIM + h * 32;
        const float* ea = emb + (size_t)bi1 * D_DIM + h * 32;
        const float* eb = emb + (size_t)bi2 * D_DIM + h * 32;
        float s1 = 0.f, s2 = 0.f;
        #pragma unroll
        for (int i = 0; i < 8; i++) {
            const float4 xv = ((const float4*)xr)[i];
            const float4 av = ((const float4*)ea)[i];
            const float4 bb = ((const float4*)eb)[i];
            s1 += xv.x * av.x + xv.y * av.y + xv.z * av.z + xv.w * av.w;
            s2 += xv.x * bb.x + xv.y * bb.y + xv.z * bb.z + xv.w * bb.w;
        }
        #pragma unroll
        for (int off = 16; off <= 32; off <<= 1) {
            s1 += __shfl_xor(s1, off);
            s2 += __shfl_xor(s2, off);
        }
        const float g1 = prec * s1 - hp * e2g[bi1];
        const float g2 = prec * s2 - hp * e2g[bi2];
        const int win = (g2 > g1 || (g2 == g1 && bi2 < bi1)) ? bi2 : bi1;
        if (lane < 16) {
            out[(size_t)N_TOK * D_DIM + n0w + lane] = (float)win;
            atomicAdd(&cnt[win], 1);
        }
    }

    // ---- PV epilogue: q = qacc / Sg; write out; sum (x-q)^2 ----
    float ssl = 0.f;
    #pragma unroll
    for (int dt = 0; dt < 8; dt++) {
        #pragma unroll
        for (int j = 0; j < 4; j++) {
            const int n = n0w + 4 * h + j;
            const int d = dt * 16 + l15;
            const float q = qacc[dt][j] * inv[j];
            out[(size_t)n * D_DIM + d] = q;
            const float df = x[(size_t)n * D_DIM + d] - q;
            ssl += df * df;
        }
    }
    #pragma unroll
    for (int off = 1; off <= 32; off <<= 1) ssl += __shfl_xor(ssl, off);
    if (lane == 0) atomicAdd(ws_ss, ssl);

    // ---- last-block finalization (fused k_final; saves one launch) ----
    __syncthreads();                     // all block atomics issued & drained
    if (t == 0) {
        const int prev = __hip_atomic_fetch_add((int*)(ws + WS_DONE), 1,
                            __ATOMIC_ACQ_REL, __HIP_MEMORY_SCOPE_AGENT);
        last_flag = (prev == (int)gridDim.x - 1);
    }
    __syncthreads();
    if (last_flag) {
        float s = 0.f;
        for (int i = t; i < M_EMB; i += 256) {
            const int c = __hip_atomic_load(&cnt[i], __ATOMIC_RELAXED,
                                            __HIP_MEMORY_SCOPE_AGENT);
            const float avg = (float)c * (1.f / N_TOK);
            s += avg * logf(avg + 1e-10f);
        }
        #pragma unroll
        for (int off = 32; off >= 1; off >>= 1) s += __shfl_down(s, off);
        if ((t & 63) == 0) fin[t >> 6] = s;
        __syncthreads();
        if (t == 0) {
            const float tot = fin[0] + fin[1] + fin[2] + fin[3];
            const float perp = expf(-tot);
            const float ssv = __hip_atomic_load(ws_ss, __ATOMIC_RELAXED,
                                                __HIP_MEMORY_SCOPE_AGENT);
            const float env = __hip_atomic_load(ws_ent, __ATOMIC_RELAXED,
                                                __HIP_MEMORY_SCOPE_AGENT);
            out[(size_t)N_TOK * D_DIM + N_TOK] = hp * ssv + env;
            out[(size_t)N_TOK * D_DIM + N_TOK + 1] = perp;
        }
    }
}

extern "C" void kernel_launch(void* const* d_in, const int* in_sizes, int n_in,
                              void* d_out, int out_size, void* d_ws, size_t ws_size,
                              hipStream_t stream) {
    const float* x   = (const float*)d_in[0];
    const float* emb = (const float*)d_in[1];
    const float* lvq = (const float*)d_in[2];
    const float* u   = (const float*)d_in[3];
    float* out = (float*)d_out;
    char* ws = (char*)d_ws;
    k_prep<<<dim3(M_EMB / 16), dim3(256), 0, stream>>>(emb, ws);
    k_main<<<dim3(N_TOK / 64), dim3(256), 0, stream>>>(x, emb, lvq, u, out, ws);
}

// Round 14
// 353.528 us; speedup vs baseline: 3.5486x; 1.6468x over previous
//
#include <hip/hip_runtime.h>
#include <math.h>

#define N_TOK 32768
#define M_EMB 1024
#define D_DIM 128

// workspace layout (bytes)
#define WS_EH  0                        // bf16 e_hi[1024][128]   (256 KB)
#define WS_EL  262144                   // bf16 e_lo[1024][128]   (256 KB)
#define WS_TH  524288                   // bf16 et_hi[128][1024]  (256 KB)
#define WS_TL  786432                   // bf16 et_lo[128][1024]  (256 KB)
#define WS_E2  1048576                  // float e2[1024]
#define WS_CNT (WS_E2 + 4096)           // int counts[1024]
#define WS_SS  (WS_CNT + 4096)          // float sum((x-q)^2)
#define WS_ENT (WS_SS + 4)              // float sum(p*logp)
#define WS_DONE (WS_ENT + 4)            // int: blocks-finished counter

#define QK_LDA 136                      // shorts/row: 128 + 8 pad (16B-aligned stride)
#define PV_LDA 72                       // shorts/d-row: 64 data + 8 pad

typedef float  f32x4  __attribute__((ext_vector_type(4)));
typedef short  s16x8  __attribute__((ext_vector_type(8)));
typedef short  s16x4  __attribute__((ext_vector_type(4)));
typedef __bf16 bf16x8 __attribute__((ext_vector_type(8)));

__device__ __forceinline__ ushort f2bf(float f) {
    unsigned x = __float_as_uint(f);
    unsigned r = (x + 0x7fffu + ((x >> 16) & 1u)) >> 16;
    return (ushort)r;
}
__device__ __forceinline__ float bf2f(ushort h) {
    return __uint_as_float(((unsigned)h) << 16);
}
__device__ __forceinline__ f32x4 mfma_k32(s16x8 a, s16x8 b, f32x4 c) {
    return __builtin_amdgcn_mfma_f32_16x16x32_bf16(
        __builtin_bit_cast(bf16x8, a), __builtin_bit_cast(bf16x8, b), c, 0, 0, 0);
}
__device__ __forceinline__ f32x4 mfma_k16(s16x4 a, s16x4 b, f32x4 c) {
#if __has_builtin(__builtin_amdgcn_mfma_f32_16x16x16bf16_1k)
    return __builtin_amdgcn_mfma_f32_16x16x16bf16_1k(a, b, c, 0, 0, 0);
#else
    asm("v_mfma_f32_16x16x16_bf16 %0, %1, %2, %0" : "+v"(c) : "v"(a), "v"(b));
    return c;
#endif
}

// Convert embedding to bf16 hi/lo in row-major and transposed layouts; e2; zero accums.
__global__ void k_prep(const float* __restrict__ emb, char* ws) {
    __shared__ ushort th_s[16][128];
    __shared__ ushort tl_s[16][128];
    if (blockIdx.x == 0) {
        int* cnt = (int*)(ws + WS_CNT);
        for (int i = threadIdx.x; i < M_EMB; i += 256) cnt[i] = 0;
        if (threadIdx.x == 0) {
            *(float*)(ws + WS_SS) = 0.f;
            *(float*)(ws + WS_ENT) = 0.f;
            *(int*)(ws + WS_DONE) = 0;
        }
    }
    ushort* eh = (ushort*)(ws + WS_EH);
    ushort* el = (ushort*)(ws + WS_EL);
    ushort* th = (ushort*)(ws + WS_TH);
    ushort* tl = (ushort*)(ws + WS_TL);
    float* e2 = (float*)(ws + WS_E2);
    const int m0 = blockIdx.x * 16;
    const int t = threadIdx.x;
    #pragma unroll
    for (int ii = 0; ii < 8; ii++) {
        int idx = t + ii * 256;          // 0..2047
        int mi = idx >> 7, k = idx & 127;
        float v = emb[(size_t)(m0 + mi) * D_DIM + k];
        ushort hi = f2bf(v);
        ushort lo = f2bf(v - bf2f(hi));
        eh[(size_t)(m0 + mi) * D_DIM + k] = hi;
        el[(size_t)(m0 + mi) * D_DIM + k] = lo;
        th_s[mi][k] = hi;
        tl_s[mi][k] = lo;
    }
    __syncthreads();
    {
        int k = t >> 1, half = t & 1;
        s16x8 vh, vl;
        #pragma unroll
        for (int j = 0; j < 8; j++) {
            vh[j] = (short)th_s[half * 8 + j][k];
            vl[j] = (short)tl_s[half * 8 + j][k];
        }
        *(s16x8*)(th + (size_t)k * M_EMB + m0 + half * 8) = vh;
        *(s16x8*)(tl + (size_t)k * M_EMB + m0 + half * 8) = vl;
    }
    if (t < 16) {
        float s = 0.f;
        const float* er = emb + (size_t)(m0 + t) * D_DIM;
        #pragma unroll 4
        for (int k = 0; k < 128; k++) s += er[k] * er[k];
        e2[m0 + t] = s;
    }
}

// Flash-style fused kernel; block = 4 waves x 16 rows = 64 rows, mc-synchronized.
// ROUND-13 LESSON: 1->2 waves/SIMD gave ~0 per-CU throughput gain with all pipes
// <15% busy -> bottleneck is the per-CU vector-memory request path (each wave
// issued ~24 scattered 16-line loads per subtile). FIX: stage the 32KB E-tile
// per mc ONCE per block via coalesced b128 loads into LDS; fragments then come
// from ds_read_b128 (separate high-throughput pipe). PV hi/lo interleaved
// {hi4,lo4} so one b128 feeds both PV MFMAs. Arithmetic is byte-identical to
// the round-13 passing kernel (absmax 0.03125).
__global__ __launch_bounds__(256, 2) void k_main(
    const float* __restrict__ x, const float* __restrict__ emb,
    const float* __restrict__ lvq, const float* __restrict__ u,
    float* __restrict__ out, char* __restrict__ ws)
{
    __shared__ __align__(16) ushort qk_hi[32 * QK_LDA];   // 8704 B
    __shared__ __align__(16) ushort qk_lo[32 * QK_LDA];   // 8704 B
    __shared__ __align__(16) ushort pv_i[128 * PV_LDA];   // 18432 B, {hi4,lo4}/mq
    __shared__ int last_flag;
    __shared__ float fin[4];

    const int t = threadIdx.x;
    const int w = t >> 6;            // wave 0..3, each owns 16 rows
    const int lane = t & 63;
    const int l15 = lane & 15;
    const int h = lane >> 4;
    const int n0w = blockIdx.x * 64 + w * 16;   // this wave's row base

    const float* e2g = (const float*)(ws + WS_E2);
    int* cnt = (int*)(ws + WS_CNT);
    float* ws_ss = (float*)(ws + WS_SS);
    float* ws_ent = (float*)(ws + WS_ENT);
    const ushort* EHu = (const ushort*)(ws + WS_EH);
    const ushort* ELu = (const ushort*)(ws + WS_EL);
    const ushort* THu = (const ushort*)(ws + WS_TH);
    const ushort* TLu = (const ushort*)(ws + WS_TL);

    const float prec = expf(-lvq[0]);
    const float hp = 0.5f * prec;

    // ---- x B-fragments (rows n0w + l15), split hi/lo ----
    s16x8 xh[4], xl[4];
    {
        const float* xr = x + (size_t)(n0w + l15) * D_DIM;
        #pragma unroll
        for (int ks = 0; ks < 4; ks++) {
            const int k0 = ks * 32 + h * 8;
            float4 v0 = *(const float4*)(xr + k0);
            float4 v1 = *(const float4*)(xr + k0 + 4);
            float vv[8] = {v0.x, v0.y, v0.z, v0.w, v1.x, v1.y, v1.z, v1.w};
            s16x8 hi8, lo8;
            #pragma unroll
            for (int j = 0; j < 8; j++) {
                ushort hi = f2bf(vv[j]);
                hi8[j] = (short)hi;
                lo8[j] = (short)f2bf(vv[j] - bf2f(hi));
            }
            xh[ks] = hi8;
            xl[ks] = lo8;
        }
    }

    const f32x4 zz = {0.f, 0.f, 0.f, 0.f};
    f32x4 qacc[8];
    #pragma unroll
    for (int dt = 0; dt < 8; dt++) qacc[dt] = zz;

    float S = 0.f, T = 0.f, Sg = 0.f;
    float bv1 = -INFINITY, bv2 = -INFINITY;
    int bi1 = M_EMB, bi2 = M_EMB;

    const float* urow = u + (size_t)(n0w + l15) * M_EMB;
    const float EPS = 1.1920929e-07f, OME = 0.99999988f;

    // staging indices (loop-invariant)
    const int sg_row = t >> 3;              // 0..31  (qk: 16 shorts per thread)
    const int sg_col = (t & 7) * 16;        // 0,16,...,112
    const int sg_d = t >> 1;                // 0..127 (pv)
    const int sg_half = t & 1;

    #pragma unroll 1
    for (int mc = 0; mc < 32; mc++) {
        const int mb = mc * 32;
        // u loads issued before the barriers: HBM latency hides under staging
        float4 uvv[2];
        #pragma unroll
        for (int t2 = 0; t2 < 2; t2++)
            uvv[t2] = *(const float4*)(urow + mb + t2 * 16 + h * 4);

        __syncthreads();                 // prev mc's LDS reads complete
        // ---- stage QK tile: EH/EL rows [mb, mb+32) -> qk_hi/qk_lo ----
        {
            const ushort* srch = EHu + (size_t)(mb + sg_row) * 128 + sg_col;
            const ushort* srcl = ELu + (size_t)(mb + sg_row) * 128 + sg_col;
            uint4 a = *(const uint4*)srch;
            uint4 b = *(const uint4*)(srch + 8);
            uint4 c = *(const uint4*)srcl;
            uint4 d4 = *(const uint4*)(srcl + 8);
            ushort* dh = qk_hi + sg_row * QK_LDA + sg_col;
            ushort* dl = qk_lo + sg_row * QK_LDA + sg_col;
            *(uint4*)dh = a;
            *(uint4*)(dh + 8) = b;
            *(uint4*)dl = c;
            *(uint4*)(dl + 8) = d4;
        }
        // ---- stage PV tile: TH/TL cols [mb,mb+32) -> pv_i[d][mq]{hi4,lo4} ----
        {
            const ushort* sh = THu + (size_t)sg_d * 1024 + mb + sg_half * 16;
            const ushort* sl = TLu + (size_t)sg_d * 1024 + mb + sg_half * 16;
            uint4 h0 = *(const uint4*)sh;
            uint4 h1 = *(const uint4*)(sh + 8);
            uint4 l0 = *(const uint4*)sl;
            uint4 l1 = *(const uint4*)(sl + 8);
            ushort* dst = pv_i + sg_d * PV_LDA + sg_half * 32;
            *(uint4*)(dst)      = make_uint4(h0.x, h0.y, l0.x, l0.y);
            *(uint4*)(dst + 8)  = make_uint4(h0.z, h0.w, l0.z, l0.w);
            *(uint4*)(dst + 16) = make_uint4(h1.x, h1.y, l1.x, l1.y);
            *(uint4*)(dst + 24) = make_uint4(h1.z, h1.w, l1.z, l1.w);
        }
        __syncthreads();                 // tile visible to all waves

        #pragma unroll
        for (int t2 = 0; t2 < 2; t2++) {
            const int msub = mb + t2 * 16;
            // scores: D[m = 4h+j][n = l15], 3-way bf16 split (frags from LDS)
            const ushort* qh = qk_hi + (t2 * 16 + l15) * QK_LDA + h * 8;
            const ushort* ql = qk_lo + (t2 * 16 + l15) * QK_LDA + h * 8;
            f32x4 aa = zz, ab = zz, ac = zz;
            #pragma unroll
            for (int ks = 0; ks < 4; ks++) {
                const s16x8 ah = *(const s16x8*)(qh + ks * 32);
                const s16x8 al = *(const s16x8*)(ql + ks * 32);
                aa = mfma_k32(ah, xh[ks], aa);
                ab = mfma_k32(al, xh[ks], ab);
                ac = mfma_k32(ah, xl[ks], ac);
            }
            const float4 e2v = *(const float4*)(e2g + msub + h * 4);
            const float uu[4] = {uvv[t2].x, uvv[t2].y, uvv[t2].z, uvv[t2].w};
            const float ee[4] = {e2v.x, e2v.y, e2v.z, e2v.w};
            ushort pb[4];
            #pragma unroll
            for (int j = 0; j < 4; j++) {
                const int m = msub + h * 4 + j;
                const float v = prec * (aa[j] + ab[j] + ac[j]) - hp * ee[j];
                // top-2 (ascending m within lane, keep-first ties)
                if (v > bv1) {
                    bv2 = bv1; bi2 = bi1;
                    bv1 = v; bi1 = m;
                } else if (v > bv2) {
                    bv2 = v; bi2 = m;
                }
                // entropy sums (no max shift needed: |v| <~ 40)
                const float e = __expf(v);
                S += e; T += e * v;
                // gumbel: p~ = exp(v + g) = e / (-log u); series for u->1
                const float uc = fminf(fmaxf(uu[j], EPS), OME);
                const float d1 = 1.0f - uc;
                const float Lser = d1 * (1.0f + d1 * (0.5f + d1 * (0.33333334f + d1 * 0.25f)));
                const float Lnat = -__logf(uc);
                const float L = (d1 < 0.03125f) ? Lser : Lnat;
                const float pt = e * __builtin_amdgcn_rcpf(L);
                Sg += pt;
                pb[j] = f2bf(pt);
            }
            // PV: p~ tile is already in mfma_16x16x16 A-layout (row n=l15, k=4h+j)
            s16x4 pa;
            pa[0] = (short)pb[0]; pa[1] = (short)pb[1];
            pa[2] = (short)pb[2]; pa[3] = (short)pb[3];
            const ushort* pvb = pv_i + (t2 * 4 + h) * 8;
            #pragma unroll
            for (int dt = 0; dt < 8; dt++) {
                const s16x8 pv2 = *(const s16x8*)(pvb + (dt * 16 + l15) * PV_LDA);
                const s16x4 bh = __builtin_shufflevector(pv2, pv2, 0, 1, 2, 3);
                const s16x4 bl = __builtin_shufflevector(pv2, pv2, 4, 5, 6, 7);
                qacc[dt] = mfma_k16(pa, bh, qacc[dt]);
                qacc[dt] = mfma_k16(pa, bl, qacc[dt]);
            }
        }
    }

    // ---- reduce per-row stats across h-group (lanes l, l^16, l^32, l^48) ----
    #pragma unroll
    for (int off = 16; off <= 32; off <<= 1) {
        S += __shfl_xor(S, off);
        T += __shfl_xor(T, off);
        Sg += __shfl_xor(Sg, off);
        const float ov1 = __shfl_xor(bv1, off); const int oi1 = __shfl_xor(bi1, off);
        const float ov2 = __shfl_xor(bv2, off); const int oi2 = __shfl_xor(bi2, off);
        if (ov1 > bv1 || (ov1 == bv1 && oi1 < bi1)) {
            if (bv1 > ov2 || (bv1 == ov2 && bi1 < oi2)) { bv2 = bv1; bi2 = bi1; }
            else { bv2 = ov2; bi2 = oi2; }
            bv1 = ov1; bi1 = oi1;
        } else if (ov1 > bv2 || (ov1 == bv2 && oi1 < bi2)) {
            bv2 = ov1; bi2 = oi1;
        }
    }
    float inv[4];
    #pragma unroll
    for (int j = 0; j < 4; j++)
        inv[j] = 1.0f / __shfl(Sg, 4 * h + j);

    // ---- entropy: every lane holds its row's S,T (x4 dup); 16-lane sum ----
    {
        float ent = T / S - __logf(S);
        #pragma unroll
        for (int off = 1; off <= 8; off <<= 1) ent += __shfl_xor(ent, off);
        if (lane == 0) atomicAdd(ws_ent, ent);
    }

    // ---- exact fp32 recheck of top-2 candidates; write indices ----
    {
        const float* xr = x + (size_t)(n0w + l15) * D_DIM + h * 32;
        const float* ea = emb + (size_t)bi1 * D_DIM + h * 32;
        const float* eb = emb + (size_t)bi2 * D_DIM + h * 32;
        float s1 = 0.f, s2 = 0.f;
        #pragma unroll
        for (int i = 0; i < 8; i++) {
            const float4 xv = ((const float4*)xr)[i];
            const float4 av = ((const float4*)ea)[i];
            const float4 bb = ((const float4*)eb)[i];
            s1 += xv.x * av.x + xv.y * av.y + xv.z * av.z + xv.w * av.w;
            s2 += xv.x * bb.x + xv.y * bb.y + xv.z * bb.z + xv.w * bb.w;
        }
        #pragma unroll
        for (int off = 16; off <= 32; off <<= 1) {
            s1 += __shfl_xor(s1, off);
            s2 += __shfl_xor(s2, off);
        }
        const float g1 = prec * s1 - hp * e2g[bi1];
        const float g2 = prec * s2 - hp * e2g[bi2];
        const int win = (g2 > g1 || (g2 == g1 && bi2 < bi1)) ? bi2 : bi1;
        if (lane < 16) {
            out[(size_t)N_TOK * D_DIM + n0w + lane] = (float)win;
            atomicAdd(&cnt[win], 1);
        }
    }

    // ---- PV epilogue: q = qacc / Sg; write out; sum (x-q)^2 ----
    float ssl = 0.f;
    #pragma unroll
    for (int dt = 0; dt < 8; dt++) {
        #pragma unroll
        for (int j = 0; j < 4; j++) {
            const int n = n0w + 4 * h + j;
            const int d = dt * 16 + l15;
            const float q = qacc[dt][j] * inv[j];
            out[(size_t)n * D_DIM + d] = q;
            const float df = x[(size_t)n * D_DIM + d] - q;
            ssl += df * df;
        }
    }
    #pragma unroll
    for (int off = 1; off <= 32; off <<= 1) ssl += __shfl_xor(ssl, off);
    if (lane == 0) atomicAdd(ws_ss, ssl);

    // ---- last-block finalization (fused k_final; saves one launch) ----
    __syncthreads();                     // all block atomics issued & drained
    if (t == 0) {
        const int prev = __hip_atomic_fetch_add((int*)(ws + WS_DONE), 1,
                            __ATOMIC_ACQ_REL, __HIP_MEMORY_SCOPE_AGENT);
        last_flag = (prev == (int)gridDim.x - 1);
    }
    __syncthreads();
    if (last_flag) {
        float s = 0.f;
        for (int i = t; i < M_EMB; i += 256) {
            const int c = __hip_atomic_load(&cnt[i], __ATOMIC_RELAXED,
                                            __HIP_MEMORY_SCOPE_AGENT);
            const float avg = (float)c * (1.f / N_TOK);
            s += avg * logf(avg + 1e-10f);
        }
        #pragma unroll
        for (int off = 32; off >= 1; off >>= 1) s += __shfl_down(s, off);
        if ((t & 63) == 0) fin[t >> 6] = s;
        __syncthreads();
        if (t == 0) {
            const float tot = fin[0] + fin[1] + fin[2] + fin[3];
            const float perp = expf(-tot);
            const float ssv = __hip_atomic_load(ws_ss, __ATOMIC_RELAXED,
                                                __HIP_MEMORY_SCOPE_AGENT);
            const float env = __hip_atomic_load(ws_ent, __ATOMIC_RELAXED,
                                                __HIP_MEMORY_SCOPE_AGENT);
            out[(size_t)N_TOK * D_DIM + N_TOK] = hp * ssv + env;
            out[(size_t)N_TOK * D_DIM + N_TOK + 1] = perp;
        }
    }
}

extern "C" void kernel_launch(void* const* d_in, const int* in_sizes, int n_in,
                              void* d_out, int out_size, void* d_ws, size_t ws_size,
                              hipStream_t stream) {
    const float* x   = (const float*)d_in[0];
    const float* emb = (const float*)d_in[1];
    const float* lvq = (const float*)d_in[2];
    const float* u   = (const float*)d_in[3];
    float* out = (float*)d_out;
    char* ws = (char*)d_ws;
    k_prep<<<dim3(M_EMB / 16), dim3(256), 0, stream>>>(emb, ws);
    k_main<<<dim3(N_TOK / 64), dim3(256), 0, stream>>>(x, emb, lvq, u, out, ws);
}

// Round 15
// 334.779 us; speedup vs baseline: 3.7473x; 1.0560x over previous
//
#include <hip/hip_runtime.h>
#include <math.h>

#define N_TOK 32768
#define M_EMB 1024
#define D_DIM 128

// workspace layout (bytes)
#define WS_EH  0                        // bf16 e_hi[1024][128]   (256 KB)
#define WS_EL  262144                   // bf16 e_lo[1024][128]   (256 KB)
#define WS_PVG 524288                   // bf16 pvg[128][2048]    (512 KB) {hi4,lo4}/group
#define WS_E2  1048576                  // float e2[1024]
#define WS_CNT (WS_E2 + 4096)           // int counts[1024]
#define WS_SS  (WS_CNT + 4096)          // float sum((x-q)^2)
#define WS_ENT (WS_SS + 4)              // float sum(p*logp)
#define WS_DONE (WS_ENT + 4)            // int: blocks-finished counter

typedef float  f32x4  __attribute__((ext_vector_type(4)));
typedef short  s16x8  __attribute__((ext_vector_type(8)));
typedef short  s16x4  __attribute__((ext_vector_type(4)));
typedef __bf16 bf16x8 __attribute__((ext_vector_type(8)));

__device__ __forceinline__ ushort f2bf(float f) {
    unsigned x = __float_as_uint(f);
    unsigned r = (x + 0x7fffu + ((x >> 16) & 1u)) >> 16;
    return (ushort)r;
}
__device__ __forceinline__ float bf2f(ushort h) {
    return __uint_as_float(((unsigned)h) << 16);
}
__device__ __forceinline__ f32x4 mfma_k32(s16x8 a, s16x8 b, f32x4 c) {
    return __builtin_amdgcn_mfma_f32_16x16x32_bf16(
        __builtin_bit_cast(bf16x8, a), __builtin_bit_cast(bf16x8, b), c, 0, 0, 0);
}
__device__ __forceinline__ f32x4 mfma_k16(s16x4 a, s16x4 b, f32x4 c) {
#if __has_builtin(__builtin_amdgcn_mfma_f32_16x16x16bf16_1k)
    return __builtin_amdgcn_mfma_f32_16x16x16bf16_1k(a, b, c, 0, 0, 0);
#else
    asm("v_mfma_f32_16x16x16_bf16 %0, %1, %2, %0" : "+v"(c) : "v"(a), "v"(b));
    return c;
#endif
}
// async global->LDS, 16B per lane; LDS dest = uniform base + lane*16 (linear)
__device__ __forceinline__ void gl_lds16(const void* g, void* l) {
    __builtin_amdgcn_global_load_lds(
        (const __attribute__((address_space(1))) unsigned int*)g,
        (__attribute__((address_space(3))) unsigned int*)l, 16, 0, 0);
}

// Convert embedding to bf16 hi/lo (row-major, QK source) and pvg (PV source,
// {hi4,lo4}-interleaved per 4-m group, [d][2048] shorts); e2; zero accums.
__global__ void k_prep(const float* __restrict__ emb, char* ws) {
    __shared__ ushort th_s[16][128];
    __shared__ ushort tl_s[16][128];
    if (blockIdx.x == 0) {
        int* cnt = (int*)(ws + WS_CNT);
        for (int i = threadIdx.x; i < M_EMB; i += 256) cnt[i] = 0;
        if (threadIdx.x == 0) {
            *(float*)(ws + WS_SS) = 0.f;
            *(float*)(ws + WS_ENT) = 0.f;
            *(int*)(ws + WS_DONE) = 0;
        }
    }
    ushort* eh = (ushort*)(ws + WS_EH);
    ushort* el = (ushort*)(ws + WS_EL);
    ushort* pvg = (ushort*)(ws + WS_PVG);
    float* e2 = (float*)(ws + WS_E2);
    const int m0 = blockIdx.x * 16;
    const int t = threadIdx.x;
    #pragma unroll
    for (int ii = 0; ii < 8; ii++) {
        int idx = t + ii * 256;          // 0..2047
        int mi = idx >> 7, k = idx & 127;
        float v = emb[(size_t)(m0 + mi) * D_DIM + k];
        ushort hi = f2bf(v);
        ushort lo = f2bf(v - bf2f(hi));
        eh[(size_t)(m0 + mi) * D_DIM + k] = hi;
        el[(size_t)(m0 + mi) * D_DIM + k] = lo;
        th_s[mi][k] = hi;
        tl_s[mi][k] = lo;
    }
    __syncthreads();
    {
        const int d = t >> 1;
        const int gl2 = t & 1;
        #pragma unroll
        for (int gg = 0; gg < 2; gg++) {
            const int gl = gl2 * 2 + gg;         // group-within-block 0..3
            s16x8 vv;
            #pragma unroll
            for (int kk = 0; kk < 4; kk++) {
                vv[kk]     = (short)th_s[gl * 4 + kk][d];
                vv[4 + kk] = (short)tl_s[gl * 4 + kk][d];
            }
            *(s16x8*)(pvg + (size_t)d * 2048 + ((m0 >> 2) + gl) * 8) = vv;
        }
    }
    if (t < 16) {
        float s = 0.f;
        const float* er = emb + (size_t)(m0 + t) * D_DIM;
        #pragma unroll 4
        for (int k = 0; k < 128; k++) s += er[k] * er[k];
        e2[m0 + t] = s;
    }
}

// Flash-style fused kernel; block = 4 waves x 16 rows, mc-synchronized tiles.
// ROUND-15: (1) global_load_lds async staging (no staging VALU, no VGPR trip);
// (2) double-buffered tiles, ONE barrier per mc (stage mc+1 issued before
// compute mc; barrier at end drains both); (3) XOR-swizzle byte^=((row&7)<<4)
// with pre-swizzled GLOBAL source + swizzled frag reads (LDS stays linear for
// global_load_lds -- rule: both-sides-or-neither). Kills the 10.5M bank
// conflicts the +8-short pads caused. Arithmetic identical to round-14 kernel.
__global__ __launch_bounds__(256, 2) void k_main(
    const float* __restrict__ x, const float* __restrict__ emb,
    const float* __restrict__ lvq, const float* __restrict__ u,
    float* __restrict__ out, char* __restrict__ ws)
{
    __shared__ __align__(16) ushort qkh[2][32 * 128];     // 2 x 8 KB
    __shared__ __align__(16) ushort qkl[2][32 * 128];     // 2 x 8 KB
    __shared__ __align__(16) ushort pvt[2][128 * 64];     // 2 x 16 KB
    __shared__ int last_flag;
    __shared__ float fin[4];

    const int t = threadIdx.x;
    const int w = t >> 6;            // wave 0..3, each owns 16 rows
    const int lane = t & 63;
    const int l15 = lane & 15;
    const int h = lane >> 4;
    const int n0w = blockIdx.x * 64 + w * 16;   // this wave's row base

    const float* e2g = (const float*)(ws + WS_E2);
    int* cnt = (int*)(ws + WS_CNT);
    float* ws_ss = (float*)(ws + WS_SS);
    float* ws_ent = (float*)(ws + WS_ENT);
    const char* EHb = (const char*)(ws + WS_EH);
    const char* ELb = (const char*)(ws + WS_EL);
    const char* PVGb = (const char*)(ws + WS_PVG);

    const float prec = expf(-lvq[0]);
    const float hp = 0.5f * prec;

    // ---- per-wave staging lane offsets (loop-invariant, swizzled source) ----
    // QK tile (waves 0,1): 8 KB linear LDS; s = c*1024 + lane*16; row = s>>8
    // PV tile (waves 2,3): 16 KB linear LDS; s = cg*1024 + lane*16; d = s>>7
    int offA[8];
    if (w < 2) {
        #pragma unroll
        for (int c = 0; c < 8; c++) {
            const int s = c * 1024 + lane * 16;
            offA[c] = s ^ (((s >> 8) & 7) << 4);
        }
    } else {
        #pragma unroll
        for (int c = 0; c < 8; c++) {
            const int s = ((w - 2) * 8 + c) * 1024 + lane * 16;
            const int d = s >> 7;
            offA[c] = d * 4096 + ((s ^ ((d & 7) << 4)) & 127);
        }
    }

    // ---- x B-fragments (rows n0w + l15), split hi/lo ----
    s16x8 xh[4], xl[4];
    {
        const float* xr = x + (size_t)(n0w + l15) * D_DIM;
        #pragma unroll
        for (int ks = 0; ks < 4; ks++) {
            const int k0 = ks * 32 + h * 8;
            float4 v0 = *(const float4*)(xr + k0);
            float4 v1 = *(const float4*)(xr + k0 + 4);
            float vv[8] = {v0.x, v0.y, v0.z, v0.w, v1.x, v1.y, v1.z, v1.w};
            s16x8 hi8, lo8;
            #pragma unroll
            for (int j = 0; j < 8; j++) {
                ushort hi = f2bf(vv[j]);
                hi8[j] = (short)hi;
                lo8[j] = (short)f2bf(vv[j] - bf2f(hi));
            }
            xh[ks] = hi8;
            xl[ks] = lo8;
        }
    }

    const f32x4 zz = {0.f, 0.f, 0.f, 0.f};
    f32x4 qacc[8];
    #pragma unroll
    for (int dt = 0; dt < 8; dt++) qacc[dt] = zz;

    float S = 0.f, T = 0.f, Sg = 0.f;
    float bv1 = -INFINITY, bv2 = -INFINITY;
    int bi1 = M_EMB, bi2 = M_EMB;

    const float* urow = u + (size_t)(n0w + l15) * M_EMB;
    const float EPS = 1.1920929e-07f, OME = 0.99999988f;

    // ---- staging issue (wave-role: w0=qk_hi, w1=qk_lo, w2/w3=pv halves) ----
    #define STAGE(MB, B)                                                      \
        do {                                                                  \
            if (w == 0) {                                                     \
                const char* src_ = EHb + (size_t)(MB) * 256;                  \
                _Pragma("unroll")                                             \
                for (int c_ = 0; c_ < 8; c_++)                                \
                    gl_lds16(src_ + offA[c_], &qkh[B][c_ * 512]);             \
            } else if (w == 1) {                                              \
                const char* src_ = ELb + (size_t)(MB) * 256;                  \
                _Pragma("unroll")                                             \
                for (int c_ = 0; c_ < 8; c_++)                                \
                    gl_lds16(src_ + offA[c_], &qkl[B][c_ * 512]);             \
            } else {                                                          \
                const char* src_ = PVGb + (size_t)(MB) * 4;                   \
                _Pragma("unroll")                                             \
                for (int c_ = 0; c_ < 8; c_++)                                \
                    gl_lds16(src_ + offA[c_],                                 \
                             &pvt[B][((w - 2) * 8 + c_) * 512]);              \
            }                                                                 \
        } while (0)

    STAGE(0, 0);
    __syncthreads();                 // tile 0 resident (each wave drains own vmcnt)

    int cur = 0;
    const int Mq = (l15 & 7) << 4;   // QK/PV row-swizzle mask (r&7 == l15&7)

    #pragma unroll 1
    for (int mc = 0; mc < 32; mc++) {
        const int mb = mc * 32;
        // u loads for this mc (VGPR; compiler waits at use)
        float4 uvv[2];
        #pragma unroll
        for (int t2 = 0; t2 < 2; t2++)
            uvv[t2] = *(const float4*)(urow + mb + t2 * 16 + h * 4);
        // async-issue next tile into the other buffer (overlaps compute below)
        if (mc < 31) {
            if (cur) STAGE(mb + 32, 0); else STAGE(mb + 32, 1);
        }

        #pragma unroll
        for (int t2 = 0; t2 < 2; t2++) {
            const int msub = mb + t2 * 16;
            const int r = t2 * 16 + l15;
            const char* qhB = (const char*)qkh[cur] + r * 256;
            const char* qlB = (const char*)qkl[cur] + r * 256;
            f32x4 aa = zz, ab = zz, ac = zz;
            #pragma unroll
            for (int ks = 0; ks < 4; ks++) {
                const int cb = (h * 16 + ks * 64) ^ Mq;
                const s16x8 ah = *(const s16x8*)(qhB + cb);
                const s16x8 al = *(const s16x8*)(qlB + cb);
                aa = mfma_k32(ah, xh[ks], aa);
                ab = mfma_k32(al, xh[ks], ab);
                ac = mfma_k32(ah, xl[ks], ac);
            }
            const float4 e2v = *(const float4*)(e2g + msub + h * 4);
            const float uu[4] = {uvv[t2].x, uvv[t2].y, uvv[t2].z, uvv[t2].w};
            const float ee[4] = {e2v.x, e2v.y, e2v.z, e2v.w};
            ushort pb[4];
            #pragma unroll
            for (int j = 0; j < 4; j++) {
                const int m = msub + h * 4 + j;
                const float v = prec * (aa[j] + ab[j] + ac[j]) - hp * ee[j];
                // top-2 (ascending m within lane, keep-first ties)
                if (v > bv1) {
                    bv2 = bv1; bi2 = bi1;
                    bv1 = v; bi1 = m;
                } else if (v > bv2) {
                    bv2 = v; bi2 = m;
                }
                // entropy sums (no max shift needed: |v| <~ 40)
                const float e = __expf(v);
                S += e; T += e * v;
                // gumbel: p~ = exp(v + g) = e / (-log u); series for u->1
                const float uc = fminf(fmaxf(uu[j], EPS), OME);
                const float d1 = 1.0f - uc;
                const float Lser = d1 * (1.0f + d1 * (0.5f + d1 * (0.33333334f + d1 * 0.25f)));
                const float Lnat = -__logf(uc);
                const float L = (d1 < 0.03125f) ? Lser : Lnat;
                const float pt = e * __builtin_amdgcn_rcpf(L);
                Sg += pt;
                pb[j] = f2bf(pt);
            }
            // PV: p~ tile is already in mfma_16x16x16 A-layout (row n=l15, k=4h+j)
            s16x4 pa;
            pa[0] = (short)pb[0]; pa[1] = (short)pb[1];
            pa[2] = (short)pb[2]; pa[3] = (short)pb[3];
            const char* pvB = (const char*)pvt[cur]
                            + ((l15 * 128 + (t2 * 4 + h) * 16) ^ Mq);
            #pragma unroll
            for (int dt = 0; dt < 8; dt++) {
                const s16x8 pv2 = *(const s16x8*)(pvB + dt * 2048);
                const s16x4 bh = __builtin_shufflevector(pv2, pv2, 0, 1, 2, 3);
                const s16x4 bl = __builtin_shufflevector(pv2, pv2, 4, 5, 6, 7);
                qacc[dt] = mfma_k16(pa, bh, qacc[dt]);
                qacc[dt] = mfma_k16(pa, bl, qacc[dt]);
            }
        }
        __syncthreads();             // drains next-tile loads + guards reads
        cur ^= 1;
    }
    #undef STAGE

    // ---- reduce per-row stats across h-group (lanes l, l^16, l^32, l^48) ----
    #pragma unroll
    for (int off = 16; off <= 32; off <<= 1) {
        S += __shfl_xor(S, off);
        T += __shfl_xor(T, off);
        Sg += __shfl_xor(Sg, off);
        const float ov1 = __shfl_xor(bv1, off); const int oi1 = __shfl_xor(bi1, off);
        const float ov2 = __shfl_xor(bv2, off); const int oi2 = __shfl_xor(bi2, off);
        if (ov1 > bv1 || (ov1 == bv1 && oi1 < bi1)) {
            if (bv1 > ov2 || (bv1 == ov2 && bi1 < oi2)) { bv2 = bv1; bi2 = bi1; }
            else { bv2 = ov2; bi2 = oi2; }
            bv1 = ov1; bi1 = oi1;
        } else if (ov1 > bv2 || (ov1 == bv2 && oi1 < bi2)) {
            bv2 = ov1; bi2 = oi1;
        }
    }
    float inv[4];
    #pragma unroll
    for (int j = 0; j < 4; j++)
        inv[j] = 1.0f / __shfl(Sg, 4 * h + j);

    // ---- entropy: every lane holds its row's S,T (x4 dup); 16-lane sum ----
    {
        float ent = T / S - __logf(S);
        #pragma unroll
        for (int off = 1; off <= 8; off <<= 1) ent += __shfl_xor(ent, off);
        if (lane == 0) atomicAdd(ws_ent, ent);
    }

    // ---- exact fp32 recheck of top-2 candidates; write indices ----
    {
        const float* xr = x + (size_t)(n0w + l15) * D_DIM + h * 32;
        const float* ea = emb + (size_t)bi1 * D_DIM + h * 32;
        const float* eb = emb + (size_t)bi2 * D_DIM + h * 32;
        float s1 = 0.f, s2 = 0.f;
        #pragma unroll
        for (int i = 0; i < 8; i++) {
            const float4 xv = ((const float4*)xr)[i];
            const float4 av = ((const float4*)ea)[i];
            const float4 bb = ((const float4*)eb)[i];
            s1 += xv.x * av.x + xv.y * av.y + xv.z * av.z + xv.w * av.w;
            s2 += xv.x * bb.x + xv.y * bb.y + xv.z * bb.z + xv.w * bb.w;
        }
        #pragma unroll
        for (int off = 16; off <= 32; off <<= 1) {
            s1 += __shfl_xor(s1, off);
            s2 += __shfl_xor(s2, off);
        }
        const float g1 = prec * s1 - hp * e2g[bi1];
        const float g2 = prec * s2 - hp * e2g[bi2];
        const int win = (g2 > g1 || (g2 == g1 && bi2 < bi1)) ? bi2 : bi1;
        if (lane < 16) {
            out[(size_t)N_TOK * D_DIM + n0w + lane] = (float)win;
            atomicAdd(&cnt[win], 1);
        }
    }

    // ---- PV epilogue: q = qacc / Sg; write out; sum (x-q)^2 ----
    float ssl = 0.f;
    #pragma unroll
    for (int dt = 0; dt < 8; dt++) {
        #pragma unroll
        for (int j = 0; j < 4; j++) {
            const int n = n0w + 4 * h + j;
            const int d = dt * 16 + l15;
            const float q = qacc[dt][j] * inv[j];
            out[(size_t)n * D_DIM + d] = q;
            const float df = x[(size_t)n * D_DIM + d] - q;
            ssl += df * df;
        }
    }
    #pragma unroll
    for (int off = 1; off <= 32; off <<= 1) ssl += __shfl_xor(ssl, off);
    if (lane == 0) atomicAdd(ws_ss, ssl);

    // ---- last-block finalization (fused k_final; saves one launch) ----
    __syncthreads();                     // all block atomics issued & drained
    if (t == 0) {
        const int prev = __hip_atomic_fetch_add((int*)(ws + WS_DONE), 1,
                            __ATOMIC_ACQ_REL, __HIP_MEMORY_SCOPE_AGENT);
        last_flag = (prev == (int)gridDim.x - 1);
    }
    __syncthreads();
    if (last_flag) {
        float s = 0.f;
        for (int i = t; i < M_EMB; i += 256) {
            const int c = __hip_atomic_load(&cnt[i], __ATOMIC_RELAXED,
                                            __HIP_MEMORY_SCOPE_AGENT);
            const float avg = (float)c * (1.f / N_TOK);
            s += avg * logf(avg + 1e-10f);
        }
        #pragma unroll
        for (int off = 32; off >= 1; off >>= 1) s += __shfl_down(s, off);
        if ((t & 63) == 0) fin[t >> 6] = s;
        __syncthreads();
        if (t == 0) {
            const float tot = fin[0] + fin[1] + fin[2] + fin[3];
            const float perp = expf(-tot);
            const float ssv = __hip_atomic_load(ws_ss, __ATOMIC_RELAXED,
                                                __HIP_MEMORY_SCOPE_AGENT);
            const float env = __hip_atomic_load(ws_ent, __ATOMIC_RELAXED,
                                                __HIP_MEMORY_SCOPE_AGENT);
            out[(size_t)N_TOK * D_DIM + N_TOK] = hp * ssv + env;
            out[(size_t)N_TOK * D_DIM + N_TOK + 1] = perp;
        }
    }
}

extern "C" void kernel_launch(void* const* d_in, const int* in_sizes, int n_in,
                              void* d_out, int out_size, void* d_ws, size_t ws_size,
                              hipStream_t stream) {
    const float* x   = (const float*)d_in[0];
    const float* emb = (const float*)d_in[1];
    const float* lvq = (const float*)d_in[2];
    const float* u   = (const float*)d_in[3];
    float* out = (float*)d_out;
    char* ws = (char*)d_ws;
    k_prep<<<dim3(M_EMB / 16), dim3(256), 0, stream>>>(emb, ws);
    k_main<<<dim3(N_TOK / 64), dim3(256), 0, stream>>>(x, emb, lvq, u, out, ws);
}